// Round 10
// baseline (687.760 us; speedup 1.0000x reference)
//
#include <hip/hip_runtime.h>

#define BSZ 64
#define SLN 50
#define HSD 256
#define MROW 3200          // BSZ*SLN
#define NOUT 39999         // NN-1
#define SCL  0.0625f       // 1/sqrt(256)
#define NMT 5              // m-tiles per scores block

typedef unsigned short u16;
typedef __attribute__((ext_vector_type(8))) short short8;
typedef __attribute__((ext_vector_type(4))) short s4v;
typedef __attribute__((ext_vector_type(4))) float f32x4;

typedef __attribute__((address_space(1))) const unsigned int guint;
typedef __attribute__((address_space(3))) unsigned int luint;

__device__ __forceinline__ u16 f2bf(float x){
  unsigned u = __float_as_uint(x);
  return (u16)((u + 0x7FFFu + ((u >> 16) & 1u)) >> 16);
}
__device__ __forceinline__ float bf2f(u16 h){
  return __uint_as_float((unsigned)h << 16);
}
// two 8B-aligned b64 LDS loads -> one MFMA operand (rows are 136B: not 16B-aligned)
__device__ __forceinline__ short8 ld8(const u16* p){
  s4v lo = *(const s4v*)p;
  s4v hi = *(const s4v*)(p+4);
  short8 r;
  r[0]=lo[0]; r[1]=lo[1]; r[2]=lo[2]; r[3]=lo[3];
  r[4]=hi[0]; r[5]=hi[1]; r[6]=hi[2]; r[7]=hi[3];
  return r;
}

// ---------------- gather: h0[m][d] = emb[idx[m]][d] ----------------
__global__ __launch_bounds__(256) void k_gather(const int* __restrict__ idx,
                                                const float* __restrict__ emb,
                                                float* __restrict__ h0){
  int m = blockIdx.x, t = threadIdx.x;
  h0[(size_t)m*HSD + t] = emb[(size_t)idx[m]*HSD + t];
}

// -------- generic GEMM: C[m][n] = sum_c X[m][c]*W[n][c] + bias[n] --------
__global__ __launch_bounds__(256) void k_gemm(const float* __restrict__ X, int ldx,
                                              const float* __restrict__ W, int ldw,
                                              const float* __restrict__ bias,
                                              float* __restrict__ C, int ldc, int K){
  __shared__ __align__(16) float As[16][68];
  __shared__ __align__(16) float Bs[16][68];
  const int m0 = blockIdx.x*64, n0 = blockIdx.y*64;
  const int t = threadIdx.x;
  const int tx = t & 15, ty = t >> 4;
  const int lrow = t >> 2, lseg = (t & 3) * 4;
  float acc[4][4] = {};
  for (int k0 = 0; k0 < K; k0 += 16){
    float4 av = *(const float4*)&X[(size_t)(m0+lrow)*ldx + k0 + lseg];
    float4 bv = *(const float4*)&W[(size_t)(n0+lrow)*ldw + k0 + lseg];
    As[lseg+0][lrow]=av.x; As[lseg+1][lrow]=av.y; As[lseg+2][lrow]=av.z; As[lseg+3][lrow]=av.w;
    Bs[lseg+0][lrow]=bv.x; Bs[lseg+1][lrow]=bv.y; Bs[lseg+2][lrow]=bv.z; Bs[lseg+3][lrow]=bv.w;
    __syncthreads();
    #pragma unroll
    for (int kk=0; kk<16; ++kk){
      float4 a = *(const float4*)&As[kk][ty*4];
      float4 b = *(const float4*)&Bs[kk][tx*4];
      acc[0][0] += a.x*b.x; acc[0][1] += a.x*b.y; acc[0][2] += a.x*b.z; acc[0][3] += a.x*b.w;
      acc[1][0] += a.y*b.x; acc[1][1] += a.y*b.y; acc[1][2] += a.y*b.z; acc[1][3] += a.y*b.w;
      acc[2][0] += a.z*b.x; acc[2][1] += a.z*b.y; acc[2][2] += a.z*b.z; acc[2][3] += a.z*b.w;
      acc[3][0] += a.w*b.x; acc[3][1] += a.w*b.y; acc[3][2] += a.w*b.z; acc[3][3] += a.w*b.w;
    }
    __syncthreads();
  }
  #pragma unroll
  for (int i2=0;i2<4;++i2)
    #pragma unroll
    for (int j2=0;j2<4;++j2)
      C[(size_t)(m0+ty*4+i2)*ldc + n0 + tx*4 + j2] = acc[i2][j2] + bias[n0+tx*4+j2];
}

// -------- S0[b,i,j] = SCL*Sq0[b,i]·Sk0[b,j]; T0[b,k,l] = Qt0[b,k]·Kt0[b,l] --------
__global__ __launch_bounds__(256) void k_s0t0(const float* __restrict__ proj,
                                              float* __restrict__ S0,
                                              float* __restrict__ T0){
  int b = blockIdx.x, which = blockIdx.y;
  __shared__ float Lq[50][129];
  __shared__ float Lk[50][129];
  const int offq = which ? 512 : 0;
  const int offk = which ? 768 : 256;
  const float scale = which ? 1.0f : SCL;
  float* out = which ? T0 : S0;
  const int t = threadIdx.x;
  float acc[10];
  #pragma unroll
  for (int z=0;z<10;++z) acc[z]=0.f;
  for (int c0=0;c0<HSD;c0+=128){
    __syncthreads();
    for (int e=t; e<50*128; e+=256){
      int row = e>>7, c = e&127;
      Lq[row][c] = proj[(size_t)(b*SLN+row)*1280 + offq + c0 + c];
      Lk[row][c] = proj[(size_t)(b*SLN+row)*1280 + offk + c0 + c];
    }
    __syncthreads();
    #pragma unroll
    for (int z=0;z<10;++z){
      int p = t + z*256;
      if (p < 2500){
        int i = p/50, j = p - i*50;
        float s = 0.f;
        for (int c=0;c<128;++c) s += Lq[i][c]*Lk[j][c];
        acc[z] += s;
      }
    }
  }
  #pragma unroll
  for (int z=0;z<10;++z){
    int p = t + z*256;
    if (p < 2500) out[(size_t)b*2500 + p] = acc[z]*scale;
  }
}

// -------- U0[b,i,j] = SCL * Ak0[b,j]·q3d[b,i]  (batched 50x50x256) --------
__global__ __launch_bounds__(256) void k_u0(const float* __restrict__ q3d,
                                            const float* __restrict__ proj,
                                            float* __restrict__ U0){
  int b = blockIdx.x;
  __shared__ float Lq[50][129];
  __shared__ float Lk[50][129];
  const int t = threadIdx.x;
  float acc[10];
  #pragma unroll
  for (int z=0;z<10;++z) acc[z]=0.f;
  for (int c0=0;c0<HSD;c0+=128){
    __syncthreads();
    for (int e=t; e<50*128; e+=256){
      int row = e>>7, c = e&127;
      Lq[row][c] = q3d[(size_t)(b*SLN+row)*HSD + c0 + c];
      Lk[row][c] = proj[(size_t)(b*SLN+row)*1280 + 1024 + c0 + c];
    }
    __syncthreads();
    #pragma unroll
    for (int z=0;z<10;++z){
      int p = t + z*256;
      if (p < 2500){
        int i = p/50, j = p - i*50;
        float s = 0.f;
        for (int c=0;c<128;++c) s += Lq[i][c]*Lk[j][c];
        acc[z] += s;
      }
    }
  }
  #pragma unroll
  for (int z=0;z<10;++z){
    int p = t + z*256;
    if (p < 2500) U0[(size_t)b*2500 + p] = acc[z]*SCL;
  }
}

// -------- fused stage C+D (MFMA split-bf16 version) --------
__global__ __launch_bounds__(256) void k_stageD(const float* __restrict__ S0,
                                                const float* __restrict__ m1,
                                                const float* __restrict__ T0,
                                                const float* __restrict__ m2,
                                                const float* __restrict__ h0,
                                                float* __restrict__ V2buf,
                                                float* __restrict__ D123){
  const int blk = blockIdx.x;
  const int b = blk/SLN, r = blk - b*SLN;
  __shared__ __align__(16) u16 Whi [64][68];
  __shared__ __align__(16) u16 Wthi[64][68];
  __shared__ __align__(16) u16 Wtlo[64][68];
  __shared__ __align__(16) u16 T0U [64][68];      // T0^T bf16; after ph2 holds U bf16
  __shared__ __align__(16) unsigned char uni[17920]; // tm f32[50][52] then P2hi|P2lo
  __shared__ float Wr[64];
  __shared__ float V2r[64];
  float (*tm)[52] = (float(*)[52])uni;            // 10400 B, dead after ph1
  u16 (*P2hi)[68] = (u16(*)[68])uni;              // 8704 B
  u16 (*P2lo)[68] = (u16(*)[68])(uni + 9216);     // 8704 B
  const int t = threadIdx.x;
  const int lane = t & 63, w = t >> 6;
  const int fr = lane & 15, fq = lane >> 4;

  // ---- ph0a: zero the bf16 arrays (pads must be 0 for 64-wide MFMA sums)
  {
    unsigned* a0 = (unsigned*)&Whi[0][0];
    unsigned* a1 = (unsigned*)&Wthi[0][0];
    unsigned* a2 = (unsigned*)&Wtlo[0][0];
    unsigned* a3 = (unsigned*)&T0U[0][0];
    for (int e=t; e<2176; e+=256){ a0[e]=0u; a1[e]=0u; a2[e]=0u; a3[e]=0u; }
  }
  __syncthreads();

  // ---- ph0b: T0U = T0^T (bf16); tm = S0[r,:] + m1[b,:,r,:]
  {
    const float* T0b = T0 + (size_t)b*2500;
    for (int e=t; e<2500; e+=256){
      int k = e/50, l2 = e - k*50;
      T0U[l2][k] = f2bf(T0b[e]);
    }
    const float* s0row = S0 + (size_t)b*2500 + r*50;
    const float* m1b = m1 + (size_t)b*125000 + (size_t)r*50;   // m1[b][i][r][j]
    for (int e=t; e<2500; e+=256){
      int i = e/50, j = e - i*50;
      tm[i][j] = m1b[(size_t)i*2500 + j] + s0row[j];
    }
  }
  __syncthreads();

  // ---- ph1: W = row-softmax(tm); write Whi, Wt hi/lo, Wr(fp32 row r)
  {
    int i = t>>2, s = t&3;
    if (i < 50){
      float mx = -1e30f;
      for (int j=s; j<50; j+=4) mx = fmaxf(mx, tm[i][j]);
      mx = fmaxf(mx, __shfl_xor(mx,1,64));
      mx = fmaxf(mx, __shfl_xor(mx,2,64));
      float sm = 0.f;
      for (int j=s; j<50; j+=4){ float e_ = __expf(tm[i][j]-mx); tm[i][j]=e_; sm+=e_; }
      sm += __shfl_xor(sm,1,64);
      sm += __shfl_xor(sm,2,64);
      float inv = 1.0f/sm;
      for (int j=s; j<50; j+=4){
        float p = tm[i][j]*inv;
        u16 hi = f2bf(p); u16 lo = f2bf(p - bf2f(hi));
        Whi[i][j] = hi; Wthi[j][i] = hi; Wtlo[j][i] = lo;
        if (i == r) Wr[j] = p;
      }
    }
  }
  __syncthreads();

  // ---- ph2: U-stripe = W (NT) T0U   [plain bf16]
  f32x4 uacc[4];
  #pragma unroll
  for (int ct=0;ct<4;++ct) uacc[ct] = (f32x4){0.f,0.f,0.f,0.f};
  #pragma unroll
  for (int ks=0; ks<2; ++ks){
    short8 a = ld8(&Whi[16*w + fr][ks*32 + fq*8]);
    #pragma unroll
    for (int ct=0;ct<4;++ct){
      short8 bb = ld8(&T0U[16*ct + fr][ks*32 + fq*8]);
      uacc[ct] = __builtin_amdgcn_mfma_f32_16x16x32_bf16(a, bb, uacc[ct], 0, 0, 0);
    }
  }
  __syncthreads();   // everyone done reading T0t before overwrite with U
  #pragma unroll
  for (int ct=0;ct<4;++ct)
    #pragma unroll
    for (int rr=0;rr<4;++rr)
      T0U[16*w + fq*4 + rr][16*ct + fr] = f2bf(uacc[ct][rr]);

  // ---- ph3: S-stripe = U (NT) W + m2  [plain bf16, fp32 in regs]
  f32x4 sacc[4];
  #pragma unroll
  for (int ct=0;ct<4;++ct) sacc[ct] = (f32x4){0.f,0.f,0.f,0.f};
  #pragma unroll
  for (int ks=0; ks<2; ++ks){
    short8 a = ld8(&T0U[16*w + fr][ks*32 + fq*8]);   // own stripe, self-written
    #pragma unroll
    for (int ct=0;ct<4;++ct){
      short8 bb = ld8(&Whi[16*ct + fr][ks*32 + fq*8]);
      sacc[ct] = __builtin_amdgcn_mfma_f32_16x16x32_bf16(a, bb, sacc[ct], 0, 0, 0);
    }
  }
  // ---- ph4: in-register row-softmax; write P2 hi/lo (own stripe)
  {
    const float* m2blk = m2 + (size_t)blk*2500;
    #pragma unroll
    for (int rr=0; rr<4; ++rr){
      const int row = 16*w + fq*4 + rr;
      float v[4];
      #pragma unroll
      for (int ct=0;ct<4;++ct){
        int col = 16*ct + fr;
        v[ct] = (row < 50 && col < 50) ? sacc[ct][rr] + m2blk[row*50 + col] : -1e30f;
      }
      float mx = fmaxf(fmaxf(v[0],v[1]), fmaxf(v[2],v[3]));
      mx = fmaxf(mx, __shfl_xor(mx,1,64));
      mx = fmaxf(mx, __shfl_xor(mx,2,64));
      mx = fmaxf(mx, __shfl_xor(mx,4,64));
      mx = fmaxf(mx, __shfl_xor(mx,8,64));
      float sm = 0.f;
      #pragma unroll
      for (int ct=0;ct<4;++ct){ v[ct] = __expf(v[ct]-mx); sm += v[ct]; }
      sm += __shfl_xor(sm,1,64);
      sm += __shfl_xor(sm,2,64);
      sm += __shfl_xor(sm,4,64);
      sm += __shfl_xor(sm,8,64);
      float inv = 1.0f/sm;
      #pragma unroll
      for (int ct=0;ct<4;++ct){
        float p = v[ct]*inv;
        u16 hi = f2bf(p); u16 lo = f2bf(p - bf2f(hi));
        P2hi[row][16*ct+fr] = hi;
        P2lo[row][16*ct+fr] = lo;
      }
    }
  }

  // ---- ph5: V2-stripe = P2 (NT) Wt  [3-term bf16 split]
  f32x4 vac[4];
  #pragma unroll
  for (int ct=0;ct<4;++ct) vac[ct] = (f32x4){0.f,0.f,0.f,0.f};
  #pragma unroll
  for (int ks=0; ks<2; ++ks){
    short8 ah = ld8(&P2hi[16*w + fr][ks*32 + fq*8]);  // own stripe, self-written
    short8 al = ld8(&P2lo[16*w + fr][ks*32 + fq*8]);
    #pragma unroll
    for (int ct=0;ct<4;++ct){
      short8 bh = ld8(&Wthi[16*ct + fr][ks*32 + fq*8]);
      short8 bl = ld8(&Wtlo[16*ct + fr][ks*32 + fq*8]);
      vac[ct] = __builtin_amdgcn_mfma_f32_16x16x32_bf16(ah, bh, vac[ct], 0, 0, 0);
      vac[ct] = __builtin_amdgcn_mfma_f32_16x16x32_bf16(ah, bl, vac[ct], 0, 0, 0);
      vac[ct] = __builtin_amdgcn_mfma_f32_16x16x32_bf16(al, bh, vac[ct], 0, 0, 0);
    }
  }
  {
    float* vout = V2buf + (size_t)blk*2500;
    #pragma unroll
    for (int rr=0;rr<4;++rr){
      const int row = 16*w + fq*4 + rr;
      if (row < 50){
        #pragma unroll
        for (int ct=0;ct<4;++ct){
          int col = 16*ct + fr;
          if (col < 50){
            vout[row*50 + col] = vac[ct][rr];
            if (row == r) V2r[col] = vac[ct][rr];
          }
        }
      }
    }
  }
  __syncthreads();

  // ---- ph6: d1 = Wr·h0 ; d2 = V2r·h0
  {
    float a1 = 0.f, a2 = 0.f;
    const float* h0b = h0 + (size_t)b*SLN*HSD;
    for (int j=0;j<50;++j){
      float hv = h0b[(size_t)j*HSD + t];
      a1 += Wr[j]*hv;
      a2 += V2r[j]*hv;
    }
    D123[(size_t)blk*768 + t]       = a1;   // d1
    D123[(size_t)blk*768 + 256 + t] = a2;   // d2
  }
}

// -------- stage E: sim3[k] = V2[b,k][i,:]·U0[b,i,:] + m3[b,i,i,k]; d3 --------
__global__ __launch_bounds__(256) void k_stageE(const float* __restrict__ U0,
                                                const float* __restrict__ V2buf,
                                                const float* __restrict__ m3,
                                                const float* __restrict__ h0,
                                                float* __restrict__ D123){
  const int blk = blockIdx.x;
  const int b = blk/SLN, i = blk - b*SLN;
  __shared__ float u[52];
  __shared__ float V[50][52];
  __shared__ float P3[52];
  __shared__ float w3[52];
  const int t = threadIdx.x;
  if (t < 50) u[t] = U0[(size_t)b*2500 + i*50 + t];
  for (int e=t; e<2500; e+=256){
    int k = e/50, j = e - k*50;
    V[k][j] = V2buf[((size_t)(b*SLN+k)*SLN + i)*SLN + j];
  }
  __syncthreads();
  if (t < 200){                       // sim3 (SCL folded into U0)
    int k = t>>2, s = t&3;
    float p = 0.f;
    for (int j=s; j<50; j+=4) p += V[k][j]*u[j];
    p += __shfl_xor(p,1,64); p += __shfl_xor(p,2,64);
    if (s==0) P3[k] = p + m3[((size_t)(b*SLN+i)*SLN + i)*SLN + k];
  }
  __syncthreads();
  if (t < 64){                        // softmax over 50
    float v = (t<50) ? P3[t] : -1e30f;
    float mx = v;
    for (int d=1; d<64; d<<=1) mx = fmaxf(mx, __shfl_xor(mx,d,64));
    float e_ = (t<50) ? __expf(v-mx) : 0.f;
    float sm = e_;
    for (int d=1; d<64; d<<=1) sm += __shfl_xor(sm,d,64);
    if (t<50) P3[t] = e_/sm;
  }
  __syncthreads();
  if (t < 200){                       // w3[j] = sum_k P3[k]*V[k][j]
    int j = t>>2, s = t&3;
    float p = 0.f;
    for (int k=s; k<50; k+=4) p += P3[k]*V[k][j];
    p += __shfl_xor(p,1,64); p += __shfl_xor(p,2,64);
    if (s==0) w3[j] = p;
  }
  __syncthreads();
  float acc = 0.f;
  for (int j=0;j<50;++j) acc += w3[j]*h0[(size_t)(b*SLN+j)*HSD + t];
  D123[(size_t)blk*768 + 512 + t] = acc;  // d3
}

// -------- row L2-normalize + cast to bf16; one wave per row --------
__global__ __launch_bounds__(256) void k_norm(const float* __restrict__ X,
                                              u16* __restrict__ out,
                                              int rows, int rowOffsetIn){
  int row = blockIdx.x*4 + (threadIdx.x>>6);
  if (row >= rows) return;
  int lane = threadIdx.x & 63;
  const float* x = X + (size_t)(row + rowOffsetIn)*HSD;
  float4 v = *(const float4*)&x[lane*4];
  float ss = v.x*v.x + v.y*v.y + v.z*v.z + v.w*v.w;
  for (int d=1; d<64; d<<=1) ss += __shfl_xor(ss,d,64);
  float rn = rsqrtf(ss);
  ushort4 o;
  o.x = f2bf(v.x*rn); o.y = f2bf(v.y*rn); o.z = f2bf(v.z*rn); o.w = f2bf(v.w*rn);
  *(ushort4*)&out[(size_t)row*HSD + lane*4] = o;
}

// -------- scores (MEASUREMENT build): r7 B-resident kernel, grid.x doubled --------
// blockIdx.x in [0,10): bx = blockIdx.x % 5. The two halves compute and write
// bitwise-identical values (idempotent) -> dispatch dur ~= 2x T_scores, making
// the kernel visible in rocprof top-5 WITH counters. Remove doubling next round.
__global__ __launch_bounds__(256) void k_scores(const u16* __restrict__ A,
                                                const u16* __restrict__ Bn,
                                                float* __restrict__ out){
  __shared__ __align__(16) u16 Bf[8][4096];   // 64 KB: whole K for this n-tile
  __shared__ __align__(16) u16 As[2][4096];   // 16 KB dbuf
  const int nb = blockIdx.y*128;
  const int mg = (blockIdx.x % NMT)*(NMT*128);
  const int t = threadIdx.x;
  const int l = t & 63, w = t >> 6;
  const int srow = l >> 2;                          // staging row within 16
  const int scol = ((l & 3) ^ (srow & 3)) * 8;      // pre-swizzled source unit
  const int wr = w >> 1, wc = w & 1;                // wave grid 2x2
  const int fr = l & 15, fq = l >> 4;               // fragment lane map
  const int fx = (fq ^ (fr & 3)) * 8;               // swizzled read unit

  // ---- prologue: stage all 8 B k-steps + A step 0
  #pragma unroll
  for (int ks=0; ks<8; ++ks){
    #pragma unroll
    for (int i_=0;i_<2;++i_){
      int seg = w*2 + i_;
      int row = seg*16 + srow;
      int brow = nb + row; if (brow > NOUT-1) brow = NOUT-1;
      __builtin_amdgcn_global_load_lds((guint*)&Bn[(size_t)brow*HSD + ks*32 + scol],
                                       (luint*)&Bf[ks][seg*512], 16, 0, 0);
    }
  }
  #define STAGEA(buf, s_) do{                                               \
    int m0_ = mg + ((s_)>>3)*128, k0_ = ((s_)&7)*32;                        \
    _Pragma("unroll")                                                       \
    for (int i_=0;i_<2;++i_){                                               \
      int seg_ = w*2 + i_;                                                  \
      int row_ = seg_*16 + srow;                                            \
      __builtin_amdgcn_global_load_lds(                                     \
        (guint*)&A[(size_t)(m0_+row_)*HSD + k0_ + scol],                    \
        (luint*)&As[buf][seg_*512], 16, 0, 0);                              \
    }                                                                       \
  }while(0)

  STAGEA(0, 0);

  f32x4 acc[4][4];
  #pragma unroll
  for (int m=0;m<4;++m)
    #pragma unroll
    for (int n=0;n<4;++n) acc[m][n] = (f32x4){0.f,0.f,0.f,0.f};

  for (int s=0; s<NMT*8; ++s){
    const int cur = s & 1, ks = s & 7;
    __syncthreads();                       // drains tile-s A loads (and B at s=0)
    if (s+1 < NMT*8) STAGEA(cur^1, s+1);   // prefetch next A under MFMA
    short8 af[4], bf[4];
    #pragma unroll
    for (int m=0;m<4;++m)
      af[m] = *(const short8*)&As[cur][(wr*64 + m*16 + fr)*32 + fx];
    #pragma unroll
    for (int n=0;n<4;++n)
      bf[n] = *(const short8*)&Bf[ks][(wc*64 + n*16 + fr)*32 + fx];
    #pragma unroll
    for (int m=0;m<4;++m)
      #pragma unroll
      for (int n=0;n<4;++n)
        acc[m][n] = __builtin_amdgcn_mfma_f32_16x16x32_bf16(af[m], bf[n], acc[m][n], 0, 0, 0);

    if (ks == 7){
      // ---- epilogue for m-tile (s>>3): C/D layout col=lane&15, row=(lane>>4)*4+reg
      const int mbase = mg + (s>>3)*128 + wr*64 + fq*4;
      #pragma unroll
      for (int n=0;n<4;++n){
        int col = nb + wc*64 + n*16 + fr;
        if (col < NOUT){
          #pragma unroll
          for (int m=0;m<4;++m){
            int row = mbase + m*16;
            #pragma unroll
            for (int rr=0; rr<4; ++rr)
              out[(size_t)(row+rr)*NOUT + col] = acc[m][n][rr];
          }
        }
      }
      #pragma unroll
      for (int m=0;m<4;++m)
        #pragma unroll
        for (int n=0;n<4;++n) acc[m][n] = (f32x4){0.f,0.f,0.f,0.f};
    }
  }
  #undef STAGEA
}

extern "C" void kernel_launch(void* const* d_in, const int* in_sizes, int n_in,
                              void* d_out, int out_size, void* d_ws, size_t ws_size,
                              hipStream_t stream){
  const int*   idx   = (const int*)  d_in[0];
  const float* m1    = (const float*)d_in[1];
  const float* m2    = (const float*)d_in[2];
  const float* m3    = (const float*)d_in[3];
  const float* emb   = (const float*)d_in[4];
  const float* sq_w  = (const float*)d_in[5];
  const float* sq_b  = (const float*)d_in[6];
  const float* sk_w  = (const float*)d_in[7];
  const float* sk_b  = (const float*)d_in[8];
  const float* tq_w  = (const float*)d_in[9];
  const float* tq_b  = (const float*)d_in[10];
  const float* tk_w  = (const float*)d_in[11];
  const float* tk_b  = (const float*)d_in[12];
  const float* aq_w  = (const float*)d_in[13];
  const float* aq_b  = (const float*)d_in[14];
  const float* ak_w  = (const float*)d_in[15];
  const float* ak_b  = (const float*)d_in[16];
  const float* cat_w = (const float*)d_in[17];
  const float* cat_b = (const float*)d_in[18];
  float* out = (float*)d_out;

  float* ws = (float*)d_ws;
  size_t off = 0;
  float* h0   = ws + off; off += (size_t)MROW*HSD;
  float* proj = ws + off; off += (size_t)MROW*1280;       // Sq0|Sk0|Qt0|Kt0|Ak0
  float* Wst  = ws + off; off += (size_t)1280*HSD;
  float* bst  = ws + off; off += 1280;
  float* S0   = ws + off; off += (size_t)BSZ*2500;
  float* T0   = ws + off; off += (size_t)BSZ*2500;
  float* U0   = ws + off; off += (size_t)BSZ*2500;
  float* V2   = ws + off; off += (size_t)MROW*2500;
  float* D123 = ws + off; off += (size_t)MROW*768;
  float* q3d  = ws + off; off += (size_t)MROW*HSD;
  float* a32  = ws + off; off += (size_t)MROW*HSD;
  u16*   abf  = (u16*)(ws + off); off += (size_t)MROW*HSD/2;
  u16*   bnf  = (u16*)(ws + off); off += ((size_t)NOUT*HSD+1)/2;
  (void)ws_size; (void)in_sizes; (void)n_in; (void)out_size;

  hipMemcpyAsync(Wst + 0*65536, sq_w, 65536*sizeof(float), hipMemcpyDeviceToDevice, stream);
  hipMemcpyAsync(Wst + 1*65536, sk_w, 65536*sizeof(float), hipMemcpyDeviceToDevice, stream);
  hipMemcpyAsync(Wst + 2*65536, tq_w, 65536*sizeof(float), hipMemcpyDeviceToDevice, stream);
  hipMemcpyAsync(Wst + 3*65536, tk_w, 65536*sizeof(float), hipMemcpyDeviceToDevice, stream);
  hipMemcpyAsync(Wst + 4*65536, ak_w, 65536*sizeof(float), hipMemcpyDeviceToDevice, stream);
  hipMemcpyAsync(bst + 0*256, sq_b, 256*sizeof(float), hipMemcpyDeviceToDevice, stream);
  hipMemcpyAsync(bst + 1*256, sk_b, 256*sizeof(float), hipMemcpyDeviceToDevice, stream);
  hipMemcpyAsync(bst + 2*256, tq_b, 256*sizeof(float), hipMemcpyDeviceToDevice, stream);
  hipMemcpyAsync(bst + 3*256, tk_b, 256*sizeof(float), hipMemcpyDeviceToDevice, stream);
  hipMemcpyAsync(bst + 4*256, ak_b, 256*sizeof(float), hipMemcpyDeviceToDevice, stream);

  k_gather<<<MROW, 256, 0, stream>>>(idx, emb, h0);
  k_gemm  <<<dim3(50,20), 256, 0, stream>>>(h0, HSD, Wst, HSD, bst, proj, 1280, HSD);
  k_s0t0  <<<dim3(BSZ,2), 256, 0, stream>>>(proj, S0, T0);
  k_stageD<<<MROW, 256, 0, stream>>>(S0, m1, T0, m2, h0, V2, D123);
  k_gemm  <<<dim3(50,4), 256, 0, stream>>>(D123+256, 768, aq_w, HSD, aq_b, q3d, HSD, HSD);
  k_u0    <<<BSZ, 256, 0, stream>>>(q3d, proj, U0);
  k_stageE<<<MROW, 256, 0, stream>>>(U0, V2, m3, h0, D123);
  k_gemm  <<<dim3(50,4), 256, 0, stream>>>(D123, 768, cat_w, 768, cat_b, a32, HSD, 768);
  k_norm  <<<MROW/4, 256, 0, stream>>>(a32, abf, MROW, 0);
  k_norm  <<<10000, 256, 0, stream>>>(emb, bnf, NOUT, 1);
  k_scores<<<dim3(2*NMT,313), 256, 0, stream>>>(abf, bnf, out);
}

// Round 11
// 592.187 us; speedup vs baseline: 1.1614x; 1.1614x over previous
//
#include <hip/hip_runtime.h>

#define BSZ 64
#define SLN 50
#define HSD 256
#define MROW 3200          // BSZ*SLN
#define NOUT 39999         // NN-1
#define SCL  0.0625f       // 1/sqrt(256)

typedef unsigned short u16;
typedef __attribute__((ext_vector_type(8))) short short8;
typedef __attribute__((ext_vector_type(4))) short s4v;
typedef __attribute__((ext_vector_type(4))) float f32x4;

typedef __attribute__((address_space(1))) const unsigned int guint;
typedef __attribute__((address_space(3))) unsigned int luint;

__device__ __forceinline__ u16 f2bf(float x){
  unsigned u = __float_as_uint(x);
  return (u16)((u + 0x7FFFu + ((u >> 16) & 1u)) >> 16);
}
__device__ __forceinline__ float bf2f(u16 h){
  return __uint_as_float((unsigned)h << 16);
}
// two 8B-aligned b64 LDS loads -> one MFMA operand (rows are 136B: not 16B-aligned)
__device__ __forceinline__ short8 ld8(const u16* p){
  s4v lo = *(const s4v*)p;
  s4v hi = *(const s4v*)(p+4);
  short8 r;
  r[0]=lo[0]; r[1]=lo[1]; r[2]=lo[2]; r[3]=lo[3];
  r[4]=hi[0]; r[5]=hi[1]; r[6]=hi[2]; r[7]=hi[3];
  return r;
}

// ---------------- gather: h0[m][d] = emb[idx[m]][d] ----------------
__global__ __launch_bounds__(256) void k_gather(const int* __restrict__ idx,
                                                const float* __restrict__ emb,
                                                float* __restrict__ h0){
  int m = blockIdx.x, t = threadIdx.x;
  h0[(size_t)m*HSD + t] = emb[(size_t)idx[m]*HSD + t];
}

// -------- generic GEMM: C[m][n] = sum_c X[m][c]*W[n][c] + bias[n] --------
__global__ __launch_bounds__(256) void k_gemm(const float* __restrict__ X, int ldx,
                                              const float* __restrict__ W, int ldw,
                                              const float* __restrict__ bias,
                                              float* __restrict__ C, int ldc, int K){
  __shared__ __align__(16) float As[16][68];
  __shared__ __align__(16) float Bs[16][68];
  const int m0 = blockIdx.x*64, n0 = blockIdx.y*64;
  const int t = threadIdx.x;
  const int tx = t & 15, ty = t >> 4;
  const int lrow = t >> 2, lseg = (t & 3) * 4;
  float acc[4][4] = {};
  for (int k0 = 0; k0 < K; k0 += 16){
    float4 av = *(const float4*)&X[(size_t)(m0+lrow)*ldx + k0 + lseg];
    float4 bv = *(const float4*)&W[(size_t)(n0+lrow)*ldw + k0 + lseg];
    As[lseg+0][lrow]=av.x; As[lseg+1][lrow]=av.y; As[lseg+2][lrow]=av.z; As[lseg+3][lrow]=av.w;
    Bs[lseg+0][lrow]=bv.x; Bs[lseg+1][lrow]=bv.y; Bs[lseg+2][lrow]=bv.z; Bs[lseg+3][lrow]=bv.w;
    __syncthreads();
    #pragma unroll
    for (int kk=0; kk<16; ++kk){
      float4 a = *(const float4*)&As[kk][ty*4];
      float4 b = *(const float4*)&Bs[kk][tx*4];
      acc[0][0] += a.x*b.x; acc[0][1] += a.x*b.y; acc[0][2] += a.x*b.z; acc[0][3] += a.x*b.w;
      acc[1][0] += a.y*b.x; acc[1][1] += a.y*b.y; acc[1][2] += a.y*b.z; acc[1][3] += a.y*b.w;
      acc[2][0] += a.z*b.x; acc[2][1] += a.z*b.y; acc[2][2] += a.z*b.z; acc[2][3] += a.z*b.w;
      acc[3][0] += a.w*b.x; acc[3][1] += a.w*b.y; acc[3][2] += a.w*b.z; acc[3][3] += a.w*b.w;
    }
    __syncthreads();
  }
  #pragma unroll
  for (int i2=0;i2<4;++i2)
    #pragma unroll
    for (int j2=0;j2<4;++j2)
      C[(size_t)(m0+ty*4+i2)*ldc + n0 + tx*4 + j2] = acc[i2][j2] + bias[n0+tx*4+j2];
}

// -------- S0[b,i,j] = SCL*Sq0[b,i]·Sk0[b,j]; T0[b,k,l] = Qt0[b,k]·Kt0[b,l] --------
__global__ __launch_bounds__(256) void k_s0t0(const float* __restrict__ proj,
                                              float* __restrict__ S0,
                                              float* __restrict__ T0){
  int b = blockIdx.x, which = blockIdx.y;
  __shared__ float Lq[50][129];
  __shared__ float Lk[50][129];
  const int offq = which ? 512 : 0;
  const int offk = which ? 768 : 256;
  const float scale = which ? 1.0f : SCL;
  float* out = which ? T0 : S0;
  const int t = threadIdx.x;
  float acc[10];
  #pragma unroll
  for (int z=0;z<10;++z) acc[z]=0.f;
  for (int c0=0;c0<HSD;c0+=128){
    __syncthreads();
    for (int e=t; e<50*128; e+=256){
      int row = e>>7, c = e&127;
      Lq[row][c] = proj[(size_t)(b*SLN+row)*1280 + offq + c0 + c];
      Lk[row][c] = proj[(size_t)(b*SLN+row)*1280 + offk + c0 + c];
    }
    __syncthreads();
    #pragma unroll
    for (int z=0;z<10;++z){
      int p = t + z*256;
      if (p < 2500){
        int i = p/50, j = p - i*50;
        float s = 0.f;
        for (int c=0;c<128;++c) s += Lq[i][c]*Lk[j][c];
        acc[z] += s;
      }
    }
  }
  #pragma unroll
  for (int z=0;z<10;++z){
    int p = t + z*256;
    if (p < 2500) out[(size_t)b*2500 + p] = acc[z]*scale;
  }
}

// -------- U0[b,i,j] = SCL * Ak0[b,j]·q3d[b,i]  (batched 50x50x256) --------
__global__ __launch_bounds__(256) void k_u0(const float* __restrict__ q3d,
                                            const float* __restrict__ proj,
                                            float* __restrict__ U0){
  int b = blockIdx.x;
  __shared__ float Lq[50][129];
  __shared__ float Lk[50][129];
  const int t = threadIdx.x;
  float acc[10];
  #pragma unroll
  for (int z=0;z<10;++z) acc[z]=0.f;
  for (int c0=0;c0<HSD;c0+=128){
    __syncthreads();
    for (int e=t; e<50*128; e+=256){
      int row = e>>7, c = e&127;
      Lq[row][c] = q3d[(size_t)(b*SLN+row)*HSD + c0 + c];
      Lk[row][c] = proj[(size_t)(b*SLN+row)*1280 + 1024 + c0 + c];
    }
    __syncthreads();
    #pragma unroll
    for (int z=0;z<10;++z){
      int p = t + z*256;
      if (p < 2500){
        int i = p/50, j = p - i*50;
        float s = 0.f;
        for (int c=0;c<128;++c) s += Lq[i][c]*Lk[j][c];
        acc[z] += s;
      }
    }
  }
  #pragma unroll
  for (int z=0;z<10;++z){
    int p = t + z*256;
    if (p < 2500) U0[(size_t)b*2500 + p] = acc[z]*SCL;
  }
}

// -------- fused stage C+D (MFMA split-bf16 version) --------
__global__ __launch_bounds__(256) void k_stageD(const float* __restrict__ S0,
                                                const float* __restrict__ m1,
                                                const float* __restrict__ T0,
                                                const float* __restrict__ m2,
                                                const float* __restrict__ h0,
                                                float* __restrict__ V2buf,
                                                float* __restrict__ D123){
  const int blk = blockIdx.x;
  const int b = blk/SLN, r = blk - b*SLN;
  __shared__ __align__(16) u16 Whi [64][68];
  __shared__ __align__(16) u16 Wthi[64][68];
  __shared__ __align__(16) u16 Wtlo[64][68];
  __shared__ __align__(16) u16 T0U [64][68];      // T0^T bf16; after ph2 holds U bf16
  __shared__ __align__(16) unsigned char uni[17920]; // tm f32[50][52] then P2hi|P2lo
  __shared__ float Wr[64];
  __shared__ float V2r[64];
  float (*tm)[52] = (float(*)[52])uni;            // 10400 B, dead after ph1
  u16 (*P2hi)[68] = (u16(*)[68])uni;              // 8704 B
  u16 (*P2lo)[68] = (u16(*)[68])(uni + 9216);     // 8704 B
  const int t = threadIdx.x;
  const int lane = t & 63, w = t >> 6;
  const int fr = lane & 15, fq = lane >> 4;

  // ---- ph0a: zero the bf16 arrays (pads must be 0 for 64-wide MFMA sums)
  {
    unsigned* a0 = (unsigned*)&Whi[0][0];
    unsigned* a1 = (unsigned*)&Wthi[0][0];
    unsigned* a2 = (unsigned*)&Wtlo[0][0];
    unsigned* a3 = (unsigned*)&T0U[0][0];
    for (int e=t; e<2176; e+=256){ a0[e]=0u; a1[e]=0u; a2[e]=0u; a3[e]=0u; }
  }
  __syncthreads();

  // ---- ph0b: T0U = T0^T (bf16); tm = S0[r,:] + m1[b,:,r,:]
  {
    const float* T0b = T0 + (size_t)b*2500;
    for (int e=t; e<2500; e+=256){
      int k = e/50, l2 = e - k*50;
      T0U[l2][k] = f2bf(T0b[e]);
    }
    const float* s0row = S0 + (size_t)b*2500 + r*50;
    const float* m1b = m1 + (size_t)b*125000 + (size_t)r*50;   // m1[b][i][r][j]
    for (int e=t; e<2500; e+=256){
      int i = e/50, j = e - i*50;
      tm[i][j] = m1b[(size_t)i*2500 + j] + s0row[j];
    }
  }
  __syncthreads();

  // ---- ph1: W = row-softmax(tm); write Whi, Wt hi/lo, Wr(fp32 row r)
  {
    int i = t>>2, s = t&3;
    if (i < 50){
      float mx = -1e30f;
      for (int j=s; j<50; j+=4) mx = fmaxf(mx, tm[i][j]);
      mx = fmaxf(mx, __shfl_xor(mx,1,64));
      mx = fmaxf(mx, __shfl_xor(mx,2,64));
      float sm = 0.f;
      for (int j=s; j<50; j+=4){ float e_ = __expf(tm[i][j]-mx); tm[i][j]=e_; sm+=e_; }
      sm += __shfl_xor(sm,1,64);
      sm += __shfl_xor(sm,2,64);
      float inv = 1.0f/sm;
      for (int j=s; j<50; j+=4){
        float p = tm[i][j]*inv;
        u16 hi = f2bf(p); u16 lo = f2bf(p - bf2f(hi));
        Whi[i][j] = hi; Wthi[j][i] = hi; Wtlo[j][i] = lo;
        if (i == r) Wr[j] = p;
      }
    }
  }
  __syncthreads();

  // ---- ph2: U-stripe = W (NT) T0U   [plain bf16]
  f32x4 uacc[4];
  #pragma unroll
  for (int ct=0;ct<4;++ct) uacc[ct] = (f32x4){0.f,0.f,0.f,0.f};
  #pragma unroll
  for (int ks=0; ks<2; ++ks){
    short8 a = ld8(&Whi[16*w + fr][ks*32 + fq*8]);
    #pragma unroll
    for (int ct=0;ct<4;++ct){
      short8 bb = ld8(&T0U[16*ct + fr][ks*32 + fq*8]);
      uacc[ct] = __builtin_amdgcn_mfma_f32_16x16x32_bf16(a, bb, uacc[ct], 0, 0, 0);
    }
  }
  __syncthreads();   // everyone done reading T0t before overwrite with U
  #pragma unroll
  for (int ct=0;ct<4;++ct)
    #pragma unroll
    for (int rr=0;rr<4;++rr)
      T0U[16*w + fq*4 + rr][16*ct + fr] = f2bf(uacc[ct][rr]);

  // ---- ph3: S-stripe = U (NT) W + m2  [plain bf16, fp32 in regs]
  f32x4 sacc[4];
  #pragma unroll
  for (int ct=0;ct<4;++ct) sacc[ct] = (f32x4){0.f,0.f,0.f,0.f};
  #pragma unroll
  for (int ks=0; ks<2; ++ks){
    short8 a = ld8(&T0U[16*w + fr][ks*32 + fq*8]);   // own stripe, self-written
    #pragma unroll
    for (int ct=0;ct<4;++ct){
      short8 bb = ld8(&Whi[16*ct + fr][ks*32 + fq*8]);
      sacc[ct] = __builtin_amdgcn_mfma_f32_16x16x32_bf16(a, bb, sacc[ct], 0, 0, 0);
    }
  }
  // ---- ph4: in-register row-softmax; write P2 hi/lo (own stripe)
  {
    const float* m2blk = m2 + (size_t)blk*2500;
    #pragma unroll
    for (int rr=0; rr<4; ++rr){
      const int row = 16*w + fq*4 + rr;
      float v[4];
      #pragma unroll
      for (int ct=0;ct<4;++ct){
        int col = 16*ct + fr;
        v[ct] = (row < 50 && col < 50) ? sacc[ct][rr] + m2blk[row*50 + col] : -1e30f;
      }
      float mx = fmaxf(fmaxf(v[0],v[1]), fmaxf(v[2],v[3]));
      mx = fmaxf(mx, __shfl_xor(mx,1,64));
      mx = fmaxf(mx, __shfl_xor(mx,2,64));
      mx = fmaxf(mx, __shfl_xor(mx,4,64));
      mx = fmaxf(mx, __shfl_xor(mx,8,64));
      float sm = 0.f;
      #pragma unroll
      for (int ct=0;ct<4;++ct){ v[ct] = __expf(v[ct]-mx); sm += v[ct]; }
      sm += __shfl_xor(sm,1,64);
      sm += __shfl_xor(sm,2,64);
      sm += __shfl_xor(sm,4,64);
      sm += __shfl_xor(sm,8,64);
      float inv = 1.0f/sm;
      #pragma unroll
      for (int ct=0;ct<4;++ct){
        float p = v[ct]*inv;
        u16 hi = f2bf(p); u16 lo = f2bf(p - bf2f(hi));
        P2hi[row][16*ct+fr] = hi;
        P2lo[row][16*ct+fr] = lo;
      }
    }
  }

  // ---- ph5: V2-stripe = P2 (NT) Wt  [3-term bf16 split]
  f32x4 vac[4];
  #pragma unroll
  for (int ct=0;ct<4;++ct) vac[ct] = (f32x4){0.f,0.f,0.f,0.f};
  #pragma unroll
  for (int ks=0; ks<2; ++ks){
    short8 ah = ld8(&P2hi[16*w + fr][ks*32 + fq*8]);  // own stripe, self-written
    short8 al = ld8(&P2lo[16*w + fr][ks*32 + fq*8]);
    #pragma unroll
    for (int ct=0;ct<4;++ct){
      short8 bh = ld8(&Wthi[16*ct + fr][ks*32 + fq*8]);
      short8 bl = ld8(&Wtlo[16*ct + fr][ks*32 + fq*8]);
      vac[ct] = __builtin_amdgcn_mfma_f32_16x16x32_bf16(ah, bh, vac[ct], 0, 0, 0);
      vac[ct] = __builtin_amdgcn_mfma_f32_16x16x32_bf16(ah, bl, vac[ct], 0, 0, 0);
      vac[ct] = __builtin_amdgcn_mfma_f32_16x16x32_bf16(al, bh, vac[ct], 0, 0, 0);
    }
  }
  {
    float* vout = V2buf + (size_t)blk*2500;
    #pragma unroll
    for (int rr=0;rr<4;++rr){
      const int row = 16*w + fq*4 + rr;
      if (row < 50){
        #pragma unroll
        for (int ct=0;ct<4;++ct){
          int col = 16*ct + fr;
          if (col < 50){
            vout[row*50 + col] = vac[ct][rr];
            if (row == r) V2r[col] = vac[ct][rr];
          }
        }
      }
    }
  }
  __syncthreads();

  // ---- ph6: d1 = Wr·h0 ; d2 = V2r·h0
  {
    float a1 = 0.f, a2 = 0.f;
    const float* h0b = h0 + (size_t)b*SLN*HSD;
    for (int j=0;j<50;++j){
      float hv = h0b[(size_t)j*HSD + t];
      a1 += Wr[j]*hv;
      a2 += V2r[j]*hv;
    }
    D123[(size_t)blk*768 + t]       = a1;   // d1
    D123[(size_t)blk*768 + 256 + t] = a2;   // d2
  }
}

// -------- stage E: sim3[k] = V2[b,k][i,:]·U0[b,i,:] + m3[b,i,i,k]; d3 --------
__global__ __launch_bounds__(256) void k_stageE(const float* __restrict__ U0,
                                                const float* __restrict__ V2buf,
                                                const float* __restrict__ m3,
                                                const float* __restrict__ h0,
                                                float* __restrict__ D123){
  const int blk = blockIdx.x;
  const int b = blk/SLN, i = blk - b*SLN;
  __shared__ float u[52];
  __shared__ float V[50][52];
  __shared__ float P3[52];
  __shared__ float w3[52];
  const int t = threadIdx.x;
  if (t < 50) u[t] = U0[(size_t)b*2500 + i*50 + t];
  for (int e=t; e<2500; e+=256){
    int k = e/50, j = e - k*50;
    V[k][j] = V2buf[((size_t)(b*SLN+k)*SLN + i)*SLN + j];
  }
  __syncthreads();
  if (t < 200){                       // sim3 (SCL folded into U0)
    int k = t>>2, s = t&3;
    float p = 0.f;
    for (int j=s; j<50; j+=4) p += V[k][j]*u[j];
    p += __shfl_xor(p,1,64); p += __shfl_xor(p,2,64);
    if (s==0) P3[k] = p + m3[((size_t)(b*SLN+i)*SLN + i)*SLN + k];
  }
  __syncthreads();
  if (t < 64){                        // softmax over 50
    float v = (t<50) ? P3[t] : -1e30f;
    float mx = v;
    for (int d=1; d<64; d<<=1) mx = fmaxf(mx, __shfl_xor(mx,d,64));
    float e_ = (t<50) ? __expf(v-mx) : 0.f;
    float sm = e_;
    for (int d=1; d<64; d<<=1) sm += __shfl_xor(sm,d,64);
    if (t<50) P3[t] = e_/sm;
  }
  __syncthreads();
  if (t < 200){                       // w3[j] = sum_k P3[k]*V[k][j]
    int j = t>>2, s = t&3;
    float p = 0.f;
    for (int k=s; k<50; k+=4) p += P3[k]*V[k][j];
    p += __shfl_xor(p,1,64); p += __shfl_xor(p,2,64);
    if (s==0) w3[j] = p;
  }
  __syncthreads();
  float acc = 0.f;
  for (int j=0;j<50;++j) acc += w3[j]*h0[(size_t)(b*SLN+j)*HSD + t];
  D123[(size_t)blk*768 + 512 + t] = acc;  // d3
}

// -------- row L2-normalize + cast to bf16; one wave per row --------
__global__ __launch_bounds__(256) void k_norm(const float* __restrict__ X,
                                              u16* __restrict__ out,
                                              int rows, int rowOffsetIn){
  int row = blockIdx.x*4 + (threadIdx.x>>6);
  if (row >= rows) return;
  int lane = threadIdx.x & 63;
  const float* x = X + (size_t)(row + rowOffsetIn)*HSD;
  float4 v = *(const float4*)&x[lane*4];
  float ss = v.x*v.x + v.y*v.y + v.z*v.z + v.w*v.w;
  for (int d=1; d<64; d<<=1) ss += __shfl_xor(ss,d,64);
  float rn = rsqrtf(ss);
  ushort4 o;
  o.x = f2bf(v.x*rn); o.y = f2bf(v.y*rn); o.z = f2bf(v.z*rn); o.w = f2bf(v.w*rn);
  *(ushort4*)&out[(size_t)row*HSD + lane*4] = o;
}

// -------- scores: out[m][n] = sum_k A[m,k]*B[n,k]  (bf16 MFMA, BK=64, 4 barrier-steps) --------
// 128x128 tile, BK=64 rows of 128 B, A/B double-buffered (64 KB), fully unrolled
// 4-step K loop. Rule-21 both-sides XOR swizzle (unit ^= row&7): stage reads the
// pre-swizzled global column (row&7 == lane>>3 by construction), fragment reads
// apply the same XOR -> bank spread equals BK=32 layout, math bitwise-identical.
__global__ __launch_bounds__(256) void k_scores(const u16* __restrict__ A,
                                                const u16* __restrict__ Bn,
                                                float* __restrict__ out){
  __shared__ __align__(16) u16 As[2][8192];   // 16 KB each: [128 rows][64 cols]
  __shared__ __align__(16) u16 Bs[2][8192];
  const int m0 = blockIdx.x*128;
  const int nb = blockIdx.y*128;
  const int t = threadIdx.x;
  const int l = t & 63, w = t >> 6;
  const int srow8 = l >> 3;                 // staging: row-within-8 per wave-call
  const int sux  = (l & 7) ^ srow8;         // pre-swizzled source unit (row&7==srow8)
  const int wr = w >> 1, wc = w & 1;        // wave grid 2x2
  const int fr = l & 15, fq = l >> 4;       // fragment lane map
  const int frx = fr & 7;                   // row&7 for fragment rows

  // stage K-step ks (BK=64 cols) of A and B into buffer buf.
  // call c in 0..3: rows c*32 + w*8 + srow8; LDS linear dest, swizzled global col.
  #define STAGE(buf, ks) do{                                                  \
    _Pragma("unroll")                                                         \
    for (int c_=0;c_<4;++c_){                                                 \
      int row_ = c_*32 + w*8 + srow8;                                         \
      int gcol_ = (ks)*64 + sux*8;                                            \
      __builtin_amdgcn_global_load_lds(                                       \
        (guint*)&A[(size_t)(m0+row_)*HSD + gcol_],                            \
        (luint*)&As[buf][c_*2048 + w*512], 16, 0, 0);                         \
      int brow_ = nb + row_; if (brow_ > NOUT-1) brow_ = NOUT-1;              \
      __builtin_amdgcn_global_load_lds(                                       \
        (guint*)&Bn[(size_t)brow_*HSD + gcol_],                               \
        (luint*)&Bs[buf][c_*2048 + w*512], 16, 0, 0);                         \
    }                                                                         \
  }while(0)

  STAGE(0, 0);

  f32x4 acc[4][4];
  #pragma unroll
  for (int m=0;m<4;++m)
    #pragma unroll
    for (int n=0;n<4;++n) acc[m][n] = (f32x4){0.f,0.f,0.f,0.f};

  #pragma unroll
  for (int ks=0; ks<4; ++ks){
    const int cur = ks & 1;
    __syncthreads();                    // drains stage(ks) -> tile[cur] ready
    if (ks < 3) STAGE(cur^1, ks+1);     // prefetch next under MFMA
    #pragma unroll
    for (int ch=0; ch<2; ++ch){         // two K=32 chunks per BK=64 row
      const int ux = ((ch*4 + fq) ^ frx) * 8;   // swizzled read unit (elements)
      short8 af[4], bf[4];
      #pragma unroll
      for (int m=0;m<4;++m)
        af[m] = *(const short8*)&As[cur][(wr*64 + m*16 + fr)*64 + ux];
      #pragma unroll
      for (int n=0;n<4;++n)
        bf[n] = *(const short8*)&Bs[cur][(wc*64 + n*16 + fr)*64 + ux];
      #pragma unroll
      for (int m=0;m<4;++m)
        #pragma unroll
        for (int n=0;n<4;++n)
          acc[m][n] = __builtin_amdgcn_mfma_f32_16x16x32_bf16(af[m], bf[n], acc[m][n], 0, 0, 0);
    }
  }
  #undef STAGE

  // epilogue: C/D layout col = lane&15, row = (lane>>4)*4 + reg
  const int mbase = m0 + wr*64 + fq*4;
  #pragma unroll
  for (int n=0;n<4;++n){
    int col = nb + wc*64 + n*16 + fr;
    if (col < NOUT){
      #pragma unroll
      for (int m=0;m<4;++m){
        int row = mbase + m*16;
        #pragma unroll
        for (int rr=0; rr<4; ++rr)
          out[(size_t)(row+rr)*NOUT + col] = acc[m][n][rr];
      }
    }
  }
}

extern "C" void kernel_launch(void* const* d_in, const int* in_sizes, int n_in,
                              void* d_out, int out_size, void* d_ws, size_t ws_size,
                              hipStream_t stream){
  const int*   idx   = (const int*)  d_in[0];
  const float* m1    = (const float*)d_in[1];
  const float* m2    = (const float*)d_in[2];
  const float* m3    = (const float*)d_in[3];
  const float* emb   = (const float*)d_in[4];
  const float* sq_w  = (const float*)d_in[5];
  const float* sq_b  = (const float*)d_in[6];
  const float* sk_w  = (const float*)d_in[7];
  const float* sk_b  = (const float*)d_in[8];
  const float* tq_w  = (const float*)d_in[9];
  const float* tq_b  = (const float*)d_in[10];
  const float* tk_w  = (const float*)d_in[11];
  const float* tk_b  = (const float*)d_in[12];
  const float* aq_w  = (const float*)d_in[13];
  const float* aq_b  = (const float*)d_in[14];
  const float* ak_w  = (const float*)d_in[15];
  const float* ak_b  = (const float*)d_in[16];
  const float* cat_w = (const float*)d_in[17];
  const float* cat_b = (const float*)d_in[18];
  float* out = (float*)d_out;

  float* ws = (float*)d_ws;
  size_t off = 0;
  float* h0   = ws + off; off += (size_t)MROW*HSD;
  float* proj = ws + off; off += (size_t)MROW*1280;       // Sq0|Sk0|Qt0|Kt0|Ak0
  float* Wst  = ws + off; off += (size_t)1280*HSD;
  float* bst  = ws + off; off += 1280;
  float* S0   = ws + off; off += (size_t)BSZ*2500;
  float* T0   = ws + off; off += (size_t)BSZ*2500;
  float* U0   = ws + off; off += (size_t)BSZ*2500;
  float* V2   = ws + off; off += (size_t)MROW*2500;
  float* D123 = ws + off; off += (size_t)MROW*768;
  float* q3d  = ws + off; off += (size_t)MROW*HSD;
  float* a32  = ws + off; off += (size_t)MROW*HSD;
  u16*   abf  = (u16*)(ws + off); off += (size_t)MROW*HSD/2;
  u16*   bnf  = (u16*)(ws + off); off += ((size_t)NOUT*HSD+1)/2;
  (void)ws_size; (void)in_sizes; (void)n_in; (void)out_size;

  hipMemcpyAsync(Wst + 0*65536, sq_w, 65536*sizeof(float), hipMemcpyDeviceToDevice, stream);
  hipMemcpyAsync(Wst + 1*65536, sk_w, 65536*sizeof(float), hipMemcpyDeviceToDevice, stream);
  hipMemcpyAsync(Wst + 2*65536, tq_w, 65536*sizeof(float), hipMemcpyDeviceToDevice, stream);
  hipMemcpyAsync(Wst + 3*65536, tk_w, 65536*sizeof(float), hipMemcpyDeviceToDevice, stream);
  hipMemcpyAsync(Wst + 4*65536, ak_w, 65536*sizeof(float), hipMemcpyDeviceToDevice, stream);
  hipMemcpyAsync(bst + 0*256, sq_b, 256*sizeof(float), hipMemcpyDeviceToDevice, stream);
  hipMemcpyAsync(bst + 1*256, sk_b, 256*sizeof(float), hipMemcpyDeviceToDevice, stream);
  hipMemcpyAsync(bst + 2*256, tq_b, 256*sizeof(float), hipMemcpyDeviceToDevice, stream);
  hipMemcpyAsync(bst + 3*256, tk_b, 256*sizeof(float), hipMemcpyDeviceToDevice, stream);
  hipMemcpyAsync(bst + 4*256, ak_b, 256*sizeof(float), hipMemcpyDeviceToDevice, stream);

  k_gather<<<MROW, 256, 0, stream>>>(idx, emb, h0);
  k_gemm  <<<dim3(50,20), 256, 0, stream>>>(h0, HSD, Wst, HSD, bst, proj, 1280, HSD);
  k_s0t0  <<<dim3(BSZ,2), 256, 0, stream>>>(proj, S0, T0);
  k_stageD<<<MROW, 256, 0, stream>>>(S0, m1, T0, m2, h0, V2, D123);
  k_gemm  <<<dim3(50,4), 256, 0, stream>>>(D123+256, 768, aq_w, HSD, aq_b, q3d, HSD, HSD);
  k_u0    <<<BSZ, 256, 0, stream>>>(q3d, proj, U0);
  k_stageE<<<MROW, 256, 0, stream>>>(U0, V2, m3, h0, D123);
  k_gemm  <<<dim3(50,4), 256, 0, stream>>>(D123, 768, cat_w, 768, cat_b, a32, HSD, 768);
  k_norm  <<<MROW/4, 256, 0, stream>>>(a32, abf, MROW, 0);
  k_norm  <<<10000, 256, 0, stream>>>(emb, bnf, NOUT, 1);
  k_scores<<<dim3(25,313), 256, 0, stream>>>(abf, bnf, out);
}

// Round 12
// 589.471 us; speedup vs baseline: 1.1667x; 1.0046x over previous
//
#include <hip/hip_runtime.h>

#define BSZ 64
#define SLN 50
#define HSD 256
#define MROW 3200          // BSZ*SLN
#define NOUT 39999         // NN-1
#define SCL  0.0625f       // 1/sqrt(256)

typedef unsigned short u16;
typedef __attribute__((ext_vector_type(8))) short short8;
typedef __attribute__((ext_vector_type(4))) short s4v;
typedef __attribute__((ext_vector_type(4))) float f32x4;

typedef __attribute__((address_space(1))) const unsigned int guint;
typedef __attribute__((address_space(3))) unsigned int luint;

__device__ __forceinline__ u16 f2bf(float x){
  unsigned u = __float_as_uint(x);
  return (u16)((u + 0x7FFFu + ((u >> 16) & 1u)) >> 16);
}
__device__ __forceinline__ float bf2f(u16 h){
  return __uint_as_float((unsigned)h << 16);
}
// two 8B-aligned b64 LDS loads -> one MFMA operand (rows are 136B: not 16B-aligned)
__device__ __forceinline__ short8 ld8(const u16* p){
  s4v lo = *(const s4v*)p;
  s4v hi = *(const s4v*)(p+4);
  short8 r;
  r[0]=lo[0]; r[1]=lo[1]; r[2]=lo[2]; r[3]=lo[3];
  r[4]=hi[0]; r[5]=hi[1]; r[6]=hi[2]; r[7]=hi[3];
  return r;
}

// ---------------- gather: h0[m][d] = emb[idx[m]][d] ----------------
__global__ __launch_bounds__(256) void k_gather(const int* __restrict__ idx,
                                                const float* __restrict__ emb,
                                                float* __restrict__ h0){
  int m = blockIdx.x, t = threadIdx.x;
  h0[(size_t)m*HSD + t] = emb[(size_t)idx[m]*HSD + t];
}

// -------- generic GEMM: C[m][n] = sum_c X[m][c]*W[n][c] + bias[n] --------
__global__ __launch_bounds__(256) void k_gemm(const float* __restrict__ X, int ldx,
                                              const float* __restrict__ W, int ldw,
                                              const float* __restrict__ bias,
                                              float* __restrict__ C, int ldc, int K){
  __shared__ __align__(16) float As[16][68];
  __shared__ __align__(16) float Bs[16][68];
  const int m0 = blockIdx.x*64, n0 = blockIdx.y*64;
  const int t = threadIdx.x;
  const int tx = t & 15, ty = t >> 4;
  const int lrow = t >> 2, lseg = (t & 3) * 4;
  float acc[4][4] = {};
  for (int k0 = 0; k0 < K; k0 += 16){
    float4 av = *(const float4*)&X[(size_t)(m0+lrow)*ldx + k0 + lseg];
    float4 bv = *(const float4*)&W[(size_t)(n0+lrow)*ldw + k0 + lseg];
    As[lseg+0][lrow]=av.x; As[lseg+1][lrow]=av.y; As[lseg+2][lrow]=av.z; As[lseg+3][lrow]=av.w;
    Bs[lseg+0][lrow]=bv.x; Bs[lseg+1][lrow]=bv.y; Bs[lseg+2][lrow]=bv.z; Bs[lseg+3][lrow]=bv.w;
    __syncthreads();
    #pragma unroll
    for (int kk=0; kk<16; ++kk){
      float4 a = *(const float4*)&As[kk][ty*4];
      float4 b = *(const float4*)&Bs[kk][tx*4];
      acc[0][0] += a.x*b.x; acc[0][1] += a.x*b.y; acc[0][2] += a.x*b.z; acc[0][3] += a.x*b.w;
      acc[1][0] += a.y*b.x; acc[1][1] += a.y*b.y; acc[1][2] += a.y*b.z; acc[1][3] += a.y*b.w;
      acc[2][0] += a.z*b.x; acc[2][1] += a.z*b.y; acc[2][2] += a.z*b.z; acc[2][3] += a.z*b.w;
      acc[3][0] += a.w*b.x; acc[3][1] += a.w*b.y; acc[3][2] += a.w*b.z; acc[3][3] += a.w*b.w;
    }
    __syncthreads();
  }
  #pragma unroll
  for (int i2=0;i2<4;++i2)
    #pragma unroll
    for (int j2=0;j2<4;++j2)
      C[(size_t)(m0+ty*4+i2)*ldc + n0 + tx*4 + j2] = acc[i2][j2] + bias[n0+tx*4+j2];
}

// -------- S0[b,i,j] = SCL*Sq0[b,i]·Sk0[b,j]; T0[b,k,l] = Qt0[b,k]·Kt0[b,l] --------
__global__ __launch_bounds__(256) void k_s0t0(const float* __restrict__ proj,
                                              float* __restrict__ S0,
                                              float* __restrict__ T0){
  int b = blockIdx.x, which = blockIdx.y;
  __shared__ float Lq[50][129];
  __shared__ float Lk[50][129];
  const int offq = which ? 512 : 0;
  const int offk = which ? 768 : 256;
  const float scale = which ? 1.0f : SCL;
  float* out = which ? T0 : S0;
  const int t = threadIdx.x;
  float acc[10];
  #pragma unroll
  for (int z=0;z<10;++z) acc[z]=0.f;
  for (int c0=0;c0<HSD;c0+=128){
    __syncthreads();
    for (int e=t; e<50*128; e+=256){
      int row = e>>7, c = e&127;
      Lq[row][c] = proj[(size_t)(b*SLN+row)*1280 + offq + c0 + c];
      Lk[row][c] = proj[(size_t)(b*SLN+row)*1280 + offk + c0 + c];
    }
    __syncthreads();
    #pragma unroll
    for (int z=0;z<10;++z){
      int p = t + z*256;
      if (p < 2500){
        int i = p/50, j = p - i*50;
        float s = 0.f;
        for (int c=0;c<128;++c) s += Lq[i][c]*Lk[j][c];
        acc[z] += s;
      }
    }
  }
  #pragma unroll
  for (int z=0;z<10;++z){
    int p = t + z*256;
    if (p < 2500) out[(size_t)b*2500 + p] = acc[z]*scale;
  }
}

// -------- U0[b,i,j] = SCL * Ak0[b,j]·q3d[b,i]  (batched 50x50x256) --------
__global__ __launch_bounds__(256) void k_u0(const float* __restrict__ q3d,
                                            const float* __restrict__ proj,
                                            float* __restrict__ U0){
  int b = blockIdx.x;
  __shared__ float Lq[50][129];
  __shared__ float Lk[50][129];
  const int t = threadIdx.x;
  float acc[10];
  #pragma unroll
  for (int z=0;z<10;++z) acc[z]=0.f;
  for (int c0=0;c0<HSD;c0+=128){
    __syncthreads();
    for (int e=t; e<50*128; e+=256){
      int row = e>>7, c = e&127;
      Lq[row][c] = q3d[(size_t)(b*SLN+row)*HSD + c0 + c];
      Lk[row][c] = proj[(size_t)(b*SLN+row)*1280 + 1024 + c0 + c];
    }
    __syncthreads();
    #pragma unroll
    for (int z=0;z<10;++z){
      int p = t + z*256;
      if (p < 2500){
        int i = p/50, j = p - i*50;
        float s = 0.f;
        for (int c=0;c<128;++c) s += Lq[i][c]*Lk[j][c];
        acc[z] += s;
      }
    }
  }
  #pragma unroll
  for (int z=0;z<10;++z){
    int p = t + z*256;
    if (p < 2500) U0[(size_t)b*2500 + p] = acc[z]*SCL;
  }
}

// -------- fused stage C+D (MFMA split-bf16 version) --------
__global__ __launch_bounds__(256) void k_stageD(const float* __restrict__ S0,
                                                const float* __restrict__ m1,
                                                const float* __restrict__ T0,
                                                const float* __restrict__ m2,
                                                const float* __restrict__ h0,
                                                float* __restrict__ V2buf,
                                                float* __restrict__ D123){
  const int blk = blockIdx.x;
  const int b = blk/SLN, r = blk - b*SLN;
  __shared__ __align__(16) u16 Whi [64][68];
  __shared__ __align__(16) u16 Wthi[64][68];
  __shared__ __align__(16) u16 Wtlo[64][68];
  __shared__ __align__(16) u16 T0U [64][68];      // T0^T bf16; after ph2 holds U bf16
  __shared__ __align__(16) unsigned char uni[17920]; // tm f32[50][52] then P2hi|P2lo
  __shared__ float Wr[64];
  __shared__ float V2r[64];
  float (*tm)[52] = (float(*)[52])uni;            // 10400 B, dead after ph1
  u16 (*P2hi)[68] = (u16(*)[68])uni;              // 8704 B
  u16 (*P2lo)[68] = (u16(*)[68])(uni + 9216);     // 8704 B
  const int t = threadIdx.x;
  const int lane = t & 63, w = t >> 6;
  const int fr = lane & 15, fq = lane >> 4;

  // ---- ph0a: zero the bf16 arrays (pads must be 0 for 64-wide MFMA sums)
  {
    unsigned* a0 = (unsigned*)&Whi[0][0];
    unsigned* a1 = (unsigned*)&Wthi[0][0];
    unsigned* a2 = (unsigned*)&Wtlo[0][0];
    unsigned* a3 = (unsigned*)&T0U[0][0];
    for (int e=t; e<2176; e+=256){ a0[e]=0u; a1[e]=0u; a2[e]=0u; a3[e]=0u; }
  }
  __syncthreads();

  // ---- ph0b: T0U = T0^T (bf16); tm = S0[r,:] + m1[b,:,r,:]
  {
    const float* T0b = T0 + (size_t)b*2500;
    for (int e=t; e<2500; e+=256){
      int k = e/50, l2 = e - k*50;
      T0U[l2][k] = f2bf(T0b[e]);
    }
    const float* s0row = S0 + (size_t)b*2500 + r*50;
    const float* m1b = m1 + (size_t)b*125000 + (size_t)r*50;   // m1[b][i][r][j]
    for (int e=t; e<2500; e+=256){
      int i = e/50, j = e - i*50;
      tm[i][j] = m1b[(size_t)i*2500 + j] + s0row[j];
    }
  }
  __syncthreads();

  // ---- ph1: W = row-softmax(tm); write Whi, Wt hi/lo, Wr(fp32 row r)
  {
    int i = t>>2, s = t&3;
    if (i < 50){
      float mx = -1e30f;
      for (int j=s; j<50; j+=4) mx = fmaxf(mx, tm[i][j]);
      mx = fmaxf(mx, __shfl_xor(mx,1,64));
      mx = fmaxf(mx, __shfl_xor(mx,2,64));
      float sm = 0.f;
      for (int j=s; j<50; j+=4){ float e_ = __expf(tm[i][j]-mx); tm[i][j]=e_; sm+=e_; }
      sm += __shfl_xor(sm,1,64);
      sm += __shfl_xor(sm,2,64);
      float inv = 1.0f/sm;
      for (int j=s; j<50; j+=4){
        float p = tm[i][j]*inv;
        u16 hi = f2bf(p); u16 lo = f2bf(p - bf2f(hi));
        Whi[i][j] = hi; Wthi[j][i] = hi; Wtlo[j][i] = lo;
        if (i == r) Wr[j] = p;
      }
    }
  }
  __syncthreads();

  // ---- ph2: U-stripe = W (NT) T0U   [plain bf16]
  f32x4 uacc[4];
  #pragma unroll
  for (int ct=0;ct<4;++ct) uacc[ct] = (f32x4){0.f,0.f,0.f,0.f};
  #pragma unroll
  for (int ks=0; ks<2; ++ks){
    short8 a = ld8(&Whi[16*w + fr][ks*32 + fq*8]);
    #pragma unroll
    for (int ct=0;ct<4;++ct){
      short8 bb = ld8(&T0U[16*ct + fr][ks*32 + fq*8]);
      uacc[ct] = __builtin_amdgcn_mfma_f32_16x16x32_bf16(a, bb, uacc[ct], 0, 0, 0);
    }
  }
  __syncthreads();   // everyone done reading T0t before overwrite with U
  #pragma unroll
  for (int ct=0;ct<4;++ct)
    #pragma unroll
    for (int rr=0;rr<4;++rr)
      T0U[16*w + fq*4 + rr][16*ct + fr] = f2bf(uacc[ct][rr]);

  // ---- ph3: S-stripe = U (NT) W + m2  [plain bf16, fp32 in regs]
  f32x4 sacc[4];
  #pragma unroll
  for (int ct=0;ct<4;++ct) sacc[ct] = (f32x4){0.f,0.f,0.f,0.f};
  #pragma unroll
  for (int ks=0; ks<2; ++ks){
    short8 a = ld8(&T0U[16*w + fr][ks*32 + fq*8]);   // own stripe, self-written
    #pragma unroll
    for (int ct=0;ct<4;++ct){
      short8 bb = ld8(&Whi[16*ct + fr][ks*32 + fq*8]);
      sacc[ct] = __builtin_amdgcn_mfma_f32_16x16x32_bf16(a, bb, sacc[ct], 0, 0, 0);
    }
  }
  // ---- ph4: in-register row-softmax; write P2 hi/lo (own stripe)
  {
    const float* m2blk = m2 + (size_t)blk*2500;
    #pragma unroll
    for (int rr=0; rr<4; ++rr){
      const int row = 16*w + fq*4 + rr;
      float v[4];
      #pragma unroll
      for (int ct=0;ct<4;++ct){
        int col = 16*ct + fr;
        v[ct] = (row < 50 && col < 50) ? sacc[ct][rr] + m2blk[row*50 + col] : -1e30f;
      }
      float mx = fmaxf(fmaxf(v[0],v[1]), fmaxf(v[2],v[3]));
      mx = fmaxf(mx, __shfl_xor(mx,1,64));
      mx = fmaxf(mx, __shfl_xor(mx,2,64));
      mx = fmaxf(mx, __shfl_xor(mx,4,64));
      mx = fmaxf(mx, __shfl_xor(mx,8,64));
      float sm = 0.f;
      #pragma unroll
      for (int ct=0;ct<4;++ct){ v[ct] = __expf(v[ct]-mx); sm += v[ct]; }
      sm += __shfl_xor(sm,1,64);
      sm += __shfl_xor(sm,2,64);
      sm += __shfl_xor(sm,4,64);
      sm += __shfl_xor(sm,8,64);
      float inv = 1.0f/sm;
      #pragma unroll
      for (int ct=0;ct<4;++ct){
        float p = v[ct]*inv;
        u16 hi = f2bf(p); u16 lo = f2bf(p - bf2f(hi));
        P2hi[row][16*ct+fr] = hi;
        P2lo[row][16*ct+fr] = lo;
      }
    }
  }

  // ---- ph5: V2-stripe = P2 (NT) Wt  [3-term bf16 split]
  f32x4 vac[4];
  #pragma unroll
  for (int ct=0;ct<4;++ct) vac[ct] = (f32x4){0.f,0.f,0.f,0.f};
  #pragma unroll
  for (int ks=0; ks<2; ++ks){
    short8 ah = ld8(&P2hi[16*w + fr][ks*32 + fq*8]);  // own stripe, self-written
    short8 al = ld8(&P2lo[16*w + fr][ks*32 + fq*8]);
    #pragma unroll
    for (int ct=0;ct<4;++ct){
      short8 bh = ld8(&Wthi[16*ct + fr][ks*32 + fq*8]);
      short8 bl = ld8(&Wtlo[16*ct + fr][ks*32 + fq*8]);
      vac[ct] = __builtin_amdgcn_mfma_f32_16x16x32_bf16(ah, bh, vac[ct], 0, 0, 0);
      vac[ct] = __builtin_amdgcn_mfma_f32_16x16x32_bf16(ah, bl, vac[ct], 0, 0, 0);
      vac[ct] = __builtin_amdgcn_mfma_f32_16x16x32_bf16(al, bh, vac[ct], 0, 0, 0);
    }
  }
  {
    float* vout = V2buf + (size_t)blk*2500;
    #pragma unroll
    for (int rr=0;rr<4;++rr){
      const int row = 16*w + fq*4 + rr;
      if (row < 50){
        #pragma unroll
        for (int ct=0;ct<4;++ct){
          int col = 16*ct + fr;
          if (col < 50){
            vout[row*50 + col] = vac[ct][rr];
            if (row == r) V2r[col] = vac[ct][rr];
          }
        }
      }
    }
  }
  __syncthreads();

  // ---- ph6: d1 = Wr·h0 ; d2 = V2r·h0
  {
    float a1 = 0.f, a2 = 0.f;
    const float* h0b = h0 + (size_t)b*SLN*HSD;
    for (int j=0;j<50;++j){
      float hv = h0b[(size_t)j*HSD + t];
      a1 += Wr[j]*hv;
      a2 += V2r[j]*hv;
    }
    D123[(size_t)blk*768 + t]       = a1;   // d1
    D123[(size_t)blk*768 + 256 + t] = a2;   // d2
  }
}

// -------- stage E: sim3[k] = V2[b,k][i,:]·U0[b,i,:] + m3[b,i,i,k]; d3 --------
__global__ __launch_bounds__(256) void k_stageE(const float* __restrict__ U0,
                                                const float* __restrict__ V2buf,
                                                const float* __restrict__ m3,
                                                const float* __restrict__ h0,
                                                float* __restrict__ D123){
  const int blk = blockIdx.x;
  const int b = blk/SLN, i = blk - b*SLN;
  __shared__ float u[52];
  __shared__ float V[50][52];
  __shared__ float P3[52];
  __shared__ float w3[52];
  const int t = threadIdx.x;
  if (t < 50) u[t] = U0[(size_t)b*2500 + i*50 + t];
  for (int e=t; e<2500; e+=256){
    int k = e/50, j = e - k*50;
    V[k][j] = V2buf[((size_t)(b*SLN+k)*SLN + i)*SLN + j];
  }
  __syncthreads();
  if (t < 200){                       // sim3 (SCL folded into U0)
    int k = t>>2, s = t&3;
    float p = 0.f;
    for (int j=s; j<50; j+=4) p += V[k][j]*u[j];
    p += __shfl_xor(p,1,64); p += __shfl_xor(p,2,64);
    if (s==0) P3[k] = p + m3[((size_t)(b*SLN+i)*SLN + i)*SLN + k];
  }
  __syncthreads();
  if (t < 64){                        // softmax over 50
    float v = (t<50) ? P3[t] : -1e30f;
    float mx = v;
    for (int d=1; d<64; d<<=1) mx = fmaxf(mx, __shfl_xor(mx,d,64));
    float e_ = (t<50) ? __expf(v-mx) : 0.f;
    float sm = e_;
    for (int d=1; d<64; d<<=1) sm += __shfl_xor(sm,d,64);
    if (t<50) P3[t] = e_/sm;
  }
  __syncthreads();
  if (t < 200){                       // w3[j] = sum_k P3[k]*V[k][j]
    int j = t>>2, s = t&3;
    float p = 0.f;
    for (int k=s; k<50; k+=4) p += P3[k]*V[k][j];
    p += __shfl_xor(p,1,64); p += __shfl_xor(p,2,64);
    if (s==0) w3[j] = p;
  }
  __syncthreads();
  float acc = 0.f;
  for (int j=0;j<50;++j) acc += w3[j]*h0[(size_t)(b*SLN+j)*HSD + t];
  D123[(size_t)blk*768 + 512 + t] = acc;  // d3
}

// -------- row L2-normalize + cast to bf16; one wave per row --------
__global__ __launch_bounds__(256) void k_norm(const float* __restrict__ X,
                                              u16* __restrict__ out,
                                              int rows, int rowOffsetIn){
  int row = blockIdx.x*4 + (threadIdx.x>>6);
  if (row >= rows) return;
  int lane = threadIdx.x & 63;
  const float* x = X + (size_t)(row + rowOffsetIn)*HSD;
  float4 v = *(const float4*)&x[lane*4];
  float ss = v.x*v.x + v.y*v.y + v.z*v.z + v.w*v.w;
  for (int d=1; d<64; d<<=1) ss += __shfl_xor(ss,d,64);
  float rn = rsqrtf(ss);
  ushort4 o;
  o.x = f2bf(v.x*rn); o.y = f2bf(v.y*rn); o.z = f2bf(v.z*rn); o.w = f2bf(v.w*rn);
  *(ushort4*)&out[(size_t)row*HSD + lane*4] = o;
}

// -------- scores: out[m][n] = sum_k A[m,k]*B[n,k]  (bf16 MFMA, BK=64, 4 barrier-steps) --------
// 128x128 tile, BK=64 rows of 128 B, A/B double-buffered (64 KB), fully unrolled
// 4-step K loop. Rule-21 both-sides XOR swizzle (unit ^= row&7): stage reads the
// pre-swizzled global column (row&7 == lane>>3 by construction), fragment reads
// apply the same XOR -> bank spread equals BK=32 layout, math bitwise-identical.
__global__ __launch_bounds__(256) void k_scores(const u16* __restrict__ A,
                                                const u16* __restrict__ Bn,
                                                float* __restrict__ out){
  __shared__ __align__(16) u16 As[2][8192];   // 16 KB each: [128 rows][64 cols]
  __shared__ __align__(16) u16 Bs[2][8192];
  const int m0 = blockIdx.x*128;
  const int nb = blockIdx.y*128;
  const int t = threadIdx.x;
  const int l = t & 63, w = t >> 6;
  const int srow8 = l >> 3;                 // staging: row-within-8 per wave-call
  const int sux  = (l & 7) ^ srow8;         // pre-swizzled source unit (row&7==srow8)
  const int wr = w >> 1, wc = w & 1;        // wave grid 2x2
  const int fr = l & 15, fq = l >> 4;       // fragment lane map
  const int frx = fr & 7;                   // row&7 for fragment rows

  // stage K-step ks (BK=64 cols) of A and B into buffer buf.
  // call c in 0..3: rows c*32 + w*8 + srow8; LDS linear dest, swizzled global col.
  #define STAGE(buf, ks) do{                                                  \
    _Pragma("unroll")                                                         \
    for (int c_=0;c_<4;++c_){                                                 \
      int row_ = c_*32 + w*8 + srow8;                                         \
      int gcol_ = (ks)*64 + sux*8;                                            \
      __builtin_amdgcn_global_load_lds(                                       \
        (guint*)&A[(size_t)(m0+row_)*HSD + gcol_],                            \
        (luint*)&As[buf][c_*2048 + w*512], 16, 0, 0);                         \
      int brow_ = nb + row_; if (brow_ > NOUT-1) brow_ = NOUT-1;              \
      __builtin_amdgcn_global_load_lds(                                       \
        (guint*)&Bn[(size_t)brow_*HSD + gcol_],                               \
        (luint*)&Bs[buf][c_*2048 + w*512], 16, 0, 0);                         \
    }                                                                         \
  }while(0)

  STAGE(0, 0);

  f32x4 acc[4][4];
  #pragma unroll
  for (int m=0;m<4;++m)
    #pragma unroll
    for (int n=0;n<4;++n) acc[m][n] = (f32x4){0.f,0.f,0.f,0.f};

  #pragma unroll
  for (int ks=0; ks<4; ++ks){
    const int cur = ks & 1;
    __syncthreads();                    // drains stage(ks) -> tile[cur] ready
    if (ks < 3) STAGE(cur^1, ks+1);     // prefetch next under MFMA
    #pragma unroll
    for (int ch=0; ch<2; ++ch){         // two K=32 chunks per BK=64 row
      const int ux = ((ch*4 + fq) ^ frx) * 8;   // swizzled read unit (elements)
      short8 af[4], bf[4];
      #pragma unroll
      for (int m=0;m<4;++m)
        af[m] = *(const short8*)&As[cur][(wr*64 + m*16 + fr)*64 + ux];
      #pragma unroll
      for (int n=0;n<4;++n)
        bf[n] = *(const short8*)&Bs[cur][(wc*64 + n*16 + fr)*64 + ux];
      #pragma unroll
      for (int m=0;m<4;++m)
        #pragma unroll
        for (int n=0;n<4;++n)
          acc[m][n] = __builtin_amdgcn_mfma_f32_16x16x32_bf16(af[m], bf[n], acc[m][n], 0, 0, 0);
    }
  }
  #undef STAGE

  // epilogue: C/D layout col = lane&15, row = (lane>>4)*4 + reg
  const int mbase = m0 + wr*64 + fq*4;
  #pragma unroll
  for (int n=0;n<4;++n){
    int col = nb + wc*64 + n*16 + fr;
    if (col < NOUT){
      #pragma unroll
      for (int m=0;m<4;++m){
        int row = mbase + m*16;
        #pragma unroll
        for (int rr=0; rr<4; ++rr)
          out[(size_t)(row+rr)*NOUT + col] = acc[m][n][rr];
      }
    }
  }
}

extern "C" void kernel_launch(void* const* d_in, const int* in_sizes, int n_in,
                              void* d_out, int out_size, void* d_ws, size_t ws_size,
                              hipStream_t stream){
  const int*   idx   = (const int*)  d_in[0];
  const float* m1    = (const float*)d_in[1];
  const float* m2    = (const float*)d_in[2];
  const float* m3    = (const float*)d_in[3];
  const float* emb   = (const float*)d_in[4];
  const float* sq_w  = (const float*)d_in[5];
  const float* sq_b  = (const float*)d_in[6];
  const float* sk_w  = (const float*)d_in[7];
  const float* sk_b  = (const float*)d_in[8];
  const float* tq_w  = (const float*)d_in[9];
  const float* tq_b  = (const float*)d_in[10];
  const float* tk_w  = (const float*)d_in[11];
  const float* tk_b  = (const float*)d_in[12];
  const float* aq_w  = (const float*)d_in[13];
  const float* aq_b  = (const float*)d_in[14];
  const float* ak_w  = (const float*)d_in[15];
  const float* ak_b  = (const float*)d_in[16];
  const float* cat_w = (const float*)d_in[17];
  const float* cat_b = (const float*)d_in[18];
  float* out = (float*)d_out;

  float* ws = (float*)d_ws;
  size_t off = 0;
  float* h0   = ws + off; off += (size_t)MROW*HSD;
  float* proj = ws + off; off += (size_t)MROW*1280;       // Sq0|Sk0|Qt0|Kt0|Ak0
  float* Wst  = ws + off; off += (size_t)1280*HSD;
  float* bst  = ws + off; off += 1280;
  float* S0   = ws + off; off += (size_t)BSZ*2500;
  float* T0   = ws + off; off += (size_t)BSZ*2500;
  float* U0   = ws + off; off += (size_t)BSZ*2500;
  float* V2   = ws + off; off += (size_t)MROW*2500;
  float* D123 = ws + off; off += (size_t)MROW*768;
  float* q3d  = ws + off; off += (size_t)MROW*HSD;
  float* a32  = ws + off; off += (size_t)MROW*HSD;
  u16*   abf  = (u16*)(ws + off); off += (size_t)MROW*HSD/2;
  u16*   bnf  = (u16*)(ws + off); off += ((size_t)NOUT*HSD+1)/2;
  (void)ws_size; (void)in_sizes; (void)n_in; (void)out_size;

  hipMemcpyAsync(Wst + 0*65536, sq_w, 65536*sizeof(float), hipMemcpyDeviceToDevice, stream);
  hipMemcpyAsync(Wst + 1*65536, sk_w, 65536*sizeof(float), hipMemcpyDeviceToDevice, stream);
  hipMemcpyAsync(Wst + 2*65536, tq_w, 65536*sizeof(float), hipMemcpyDeviceToDevice, stream);
  hipMemcpyAsync(Wst + 3*65536, tk_w, 65536*sizeof(float), hipMemcpyDeviceToDevice, stream);
  hipMemcpyAsync(Wst + 4*65536, ak_w, 65536*sizeof(float), hipMemcpyDeviceToDevice, stream);
  hipMemcpyAsync(bst + 0*256, sq_b, 256*sizeof(float), hipMemcpyDeviceToDevice, stream);
  hipMemcpyAsync(bst + 1*256, sk_b, 256*sizeof(float), hipMemcpyDeviceToDevice, stream);
  hipMemcpyAsync(bst + 2*256, tq_b, 256*sizeof(float), hipMemcpyDeviceToDevice, stream);
  hipMemcpyAsync(bst + 3*256, tk_b, 256*sizeof(float), hipMemcpyDeviceToDevice, stream);
  hipMemcpyAsync(bst + 4*256, ak_b, 256*sizeof(float), hipMemcpyDeviceToDevice, stream);

  k_gather<<<MROW, 256, 0, stream>>>(idx, emb, h0);
  k_gemm  <<<dim3(50,20), 256, 0, stream>>>(h0, HSD, Wst, HSD, bst, proj, 1280, HSD);
  k_s0t0  <<<dim3(BSZ,2), 256, 0, stream>>>(proj, S0, T0);
  k_stageD<<<MROW, 256, 0, stream>>>(S0, m1, T0, m2, h0, V2, D123);
  k_gemm  <<<dim3(50,4), 256, 0, stream>>>(D123+256, 768, aq_w, HSD, aq_b, q3d, HSD, HSD);
  k_u0    <<<BSZ, 256, 0, stream>>>(q3d, proj, U0);
  k_stageE<<<MROW, 256, 0, stream>>>(U0, V2, m3, h0, D123);
  k_gemm  <<<dim3(50,4), 256, 0, stream>>>(D123, 768, cat_w, 768, cat_b, a32, HSD, 768);
  k_norm  <<<MROW/4, 256, 0, stream>>>(a32, abf, MROW, 0);
  k_norm  <<<10000, 256, 0, stream>>>(emb, bnf, NOUT, 1);
  k_scores<<<dim3(25,313), 256, 0, stream>>>(abf, bnf, out);
}

// Round 13
// 551.276 us; speedup vs baseline: 1.2476x; 1.0693x over previous
//
#include <hip/hip_runtime.h>

#define BSZ 64
#define SLN 50
#define HSD 256
#define MROW 3200          // BSZ*SLN
#define NOUT 39999         // NN-1
#define SCL  0.0625f       // 1/sqrt(256)
#define NMT 5              // m-tiles per scores block

typedef unsigned short u16;
typedef __attribute__((ext_vector_type(8))) short short8;
typedef __attribute__((ext_vector_type(4))) short s4v;
typedef __attribute__((ext_vector_type(4))) float f32x4;

typedef __attribute__((address_space(1))) const unsigned int guint;
typedef __attribute__((address_space(3))) unsigned int luint;

__device__ __forceinline__ u16 f2bf(float x){
  unsigned u = __float_as_uint(x);
  return (u16)((u + 0x7FFFu + ((u >> 16) & 1u)) >> 16);
}
__device__ __forceinline__ float bf2f(u16 h){
  return __uint_as_float((unsigned)h << 16);
}
// two 8B-aligned b64 LDS loads -> one MFMA operand (rows are 136B: not 16B-aligned)
__device__ __forceinline__ short8 ld8(const u16* p){
  s4v lo = *(const s4v*)p;
  s4v hi = *(const s4v*)(p+4);
  short8 r;
  r[0]=lo[0]; r[1]=lo[1]; r[2]=lo[2]; r[3]=lo[3];
  r[4]=hi[0]; r[5]=hi[1]; r[6]=hi[2]; r[7]=hi[3];
  return r;
}

// ---------------- gather: h0[m][d] = emb[idx[m]][d] ----------------
__global__ __launch_bounds__(256) void k_gather(const int* __restrict__ idx,
                                                const float* __restrict__ emb,
                                                float* __restrict__ h0){
  int m = blockIdx.x, t = threadIdx.x;
  h0[(size_t)m*HSD + t] = emb[(size_t)idx[m]*HSD + t];
}

// -------- generic GEMM: C[m][n] = sum_c X[m][c]*W[n][c] + bias[n] --------
__global__ __launch_bounds__(256) void k_gemm(const float* __restrict__ X, int ldx,
                                              const float* __restrict__ W, int ldw,
                                              const float* __restrict__ bias,
                                              float* __restrict__ C, int ldc, int K){
  __shared__ __align__(16) float As[16][68];
  __shared__ __align__(16) float Bs[16][68];
  const int m0 = blockIdx.x*64, n0 = blockIdx.y*64;
  const int t = threadIdx.x;
  const int tx = t & 15, ty = t >> 4;
  const int lrow = t >> 2, lseg = (t & 3) * 4;
  float acc[4][4] = {};
  for (int k0 = 0; k0 < K; k0 += 16){
    float4 av = *(const float4*)&X[(size_t)(m0+lrow)*ldx + k0 + lseg];
    float4 bv = *(const float4*)&W[(size_t)(n0+lrow)*ldw + k0 + lseg];
    As[lseg+0][lrow]=av.x; As[lseg+1][lrow]=av.y; As[lseg+2][lrow]=av.z; As[lseg+3][lrow]=av.w;
    Bs[lseg+0][lrow]=bv.x; Bs[lseg+1][lrow]=bv.y; Bs[lseg+2][lrow]=bv.z; Bs[lseg+3][lrow]=bv.w;
    __syncthreads();
    #pragma unroll
    for (int kk=0; kk<16; ++kk){
      float4 a = *(const float4*)&As[kk][ty*4];
      float4 b = *(const float4*)&Bs[kk][tx*4];
      acc[0][0] += a.x*b.x; acc[0][1] += a.x*b.y; acc[0][2] += a.x*b.z; acc[0][3] += a.x*b.w;
      acc[1][0] += a.y*b.x; acc[1][1] += a.y*b.y; acc[1][2] += a.y*b.z; acc[1][3] += a.y*b.w;
      acc[2][0] += a.z*b.x; acc[2][1] += a.z*b.y; acc[2][2] += a.z*b.z; acc[2][3] += a.z*b.w;
      acc[3][0] += a.w*b.x; acc[3][1] += a.w*b.y; acc[3][2] += a.w*b.z; acc[3][3] += a.w*b.w;
    }
    __syncthreads();
  }
  #pragma unroll
  for (int i2=0;i2<4;++i2)
    #pragma unroll
    for (int j2=0;j2<4;++j2)
      C[(size_t)(m0+ty*4+i2)*ldc + n0 + tx*4 + j2] = acc[i2][j2] + bias[n0+tx*4+j2];
}

// -------- S0[b,i,j] = SCL*Sq0[b,i]·Sk0[b,j]; T0[b,k,l] = Qt0[b,k]·Kt0[b,l] --------
__global__ __launch_bounds__(256) void k_s0t0(const float* __restrict__ proj,
                                              float* __restrict__ S0,
                                              float* __restrict__ T0){
  int b = blockIdx.x, which = blockIdx.y;
  __shared__ float Lq[50][129];
  __shared__ float Lk[50][129];
  const int offq = which ? 512 : 0;
  const int offk = which ? 768 : 256;
  const float scale = which ? 1.0f : SCL;
  float* out = which ? T0 : S0;
  const int t = threadIdx.x;
  float acc[10];
  #pragma unroll
  for (int z=0;z<10;++z) acc[z]=0.f;
  for (int c0=0;c0<HSD;c0+=128){
    __syncthreads();
    for (int e=t; e<50*128; e+=256){
      int row = e>>7, c = e&127;
      Lq[row][c] = proj[(size_t)(b*SLN+row)*1280 + offq + c0 + c];
      Lk[row][c] = proj[(size_t)(b*SLN+row)*1280 + offk + c0 + c];
    }
    __syncthreads();
    #pragma unroll
    for (int z=0;z<10;++z){
      int p = t + z*256;
      if (p < 2500){
        int i = p/50, j = p - i*50;
        float s = 0.f;
        for (int c=0;c<128;++c) s += Lq[i][c]*Lk[j][c];
        acc[z] += s;
      }
    }
  }
  #pragma unroll
  for (int z=0;z<10;++z){
    int p = t + z*256;
    if (p < 2500) out[(size_t)b*2500 + p] = acc[z]*scale;
  }
}

// -------- U0[b,i,j] = SCL * Ak0[b,j]·q3d[b,i]  (batched 50x50x256) --------
__global__ __launch_bounds__(256) void k_u0(const float* __restrict__ q3d,
                                            const float* __restrict__ proj,
                                            float* __restrict__ U0){
  int b = blockIdx.x;
  __shared__ float Lq[50][129];
  __shared__ float Lk[50][129];
  const int t = threadIdx.x;
  float acc[10];
  #pragma unroll
  for (int z=0;z<10;++z) acc[z]=0.f;
  for (int c0=0;c0<HSD;c0+=128){
    __syncthreads();
    for (int e=t; e<50*128; e+=256){
      int row = e>>7, c = e&127;
      Lq[row][c] = q3d[(size_t)(b*SLN+row)*HSD + c0 + c];
      Lk[row][c] = proj[(size_t)(b*SLN+row)*1280 + 1024 + c0 + c];
    }
    __syncthreads();
    #pragma unroll
    for (int z=0;z<10;++z){
      int p = t + z*256;
      if (p < 2500){
        int i = p/50, j = p - i*50;
        float s = 0.f;
        for (int c=0;c<128;++c) s += Lq[i][c]*Lk[j][c];
        acc[z] += s;
      }
    }
  }
  #pragma unroll
  for (int z=0;z<10;++z){
    int p = t + z*256;
    if (p < 2500) U0[(size_t)b*2500 + p] = acc[z]*SCL;
  }
}

// -------- fused stage C+D (MFMA split-bf16, 37 KB LDS overlay -> 4 blocks/CU) --------
// Region map:  Whi: W-hi (ph1-3) then P2lo (ph4-5)
//              uni: tm f32 (ph0b-1) -> T0^T/U bf16 (ph1.5-3) -> P2hi (ph4-5)
__global__ __launch_bounds__(256,4) void k_stageD(const float* __restrict__ S0,
                                                  const float* __restrict__ m1,
                                                  const float* __restrict__ T0,
                                                  const float* __restrict__ m2,
                                                  const float* __restrict__ h0,
                                                  float* __restrict__ V2buf,
                                                  float* __restrict__ D123){
  const int blk = blockIdx.x;
  const int b = blk/SLN, r = blk - b*SLN;
  __shared__ __align__(16) u16 Whi [64][68];          // 8704 B
  __shared__ __align__(16) u16 Wthi[64][68];          // 8704 B
  __shared__ __align__(16) u16 Wtlo[64][68];          // 8704 B
  __shared__ __align__(16) unsigned char uni[10432];  // tm | T0U/U | P2hi
  __shared__ float Wr[64];
  __shared__ float V2r[64];
  float (*tm)[52]  = (float(*)[52])uni;
  u16 (*T0U)[68]  = (u16(*)[68])uni;
  u16 (*P2hi)[68] = (u16(*)[68])uni;                  // alias of T0U region
  u16 (*P2lo)[68] = (u16(*)[68])&Whi[0][0];           // alias of Whi region
  const int t = threadIdx.x;
  const int lane = t & 63, w = t >> 6;
  const int fr = lane & 15, fq = lane >> 4;

  // ---- ph0a: zero the W arrays (pads must be 0 for 64-wide MFMA sums)
  {
    unsigned* a0 = (unsigned*)&Whi[0][0];
    unsigned* a1 = (unsigned*)&Wthi[0][0];
    unsigned* a2 = (unsigned*)&Wtlo[0][0];
    for (int e=t; e<2176; e+=256){ a0[e]=0u; a1[e]=0u; a2[e]=0u; }
  }
  __syncthreads();

  // ---- ph0b: tm = S0[r,:] + m1[b,:,r,:]
  {
    const float* s0row = S0 + (size_t)b*2500 + r*50;
    const float* m1b = m1 + (size_t)b*125000 + (size_t)r*50;   // m1[b][i][r][j]
    for (int e=t; e<2500; e+=256){
      int i = e/50, j = e - i*50;
      tm[i][j] = m1b[(size_t)i*2500 + j] + s0row[j];
    }
  }
  __syncthreads();

  // ---- ph1: W = row-softmax(tm); write Whi, Wt hi/lo, Wr(fp32 row r)
  {
    int i = t>>2, s = t&3;
    if (i < 50){
      float mx = -1e30f;
      for (int j=s; j<50; j+=4) mx = fmaxf(mx, tm[i][j]);
      mx = fmaxf(mx, __shfl_xor(mx,1,64));
      mx = fmaxf(mx, __shfl_xor(mx,2,64));
      float sm = 0.f;
      float ebuf[13];
      int nb_ = 0;
      for (int j=s; j<50; j+=4){ float e_ = __expf(tm[i][j]-mx); ebuf[nb_++]=e_; sm+=e_; }
      sm += __shfl_xor(sm,1,64);
      sm += __shfl_xor(sm,2,64);
      float inv = 1.0f/sm;
      nb_ = 0;
      for (int j=s; j<50; j+=4){
        float p = ebuf[nb_++]*inv;
        u16 hi = f2bf(p); u16 lo = f2bf(p - bf2f(hi));
        Whi[i][j] = hi; Wthi[j][i] = hi; Wtlo[j][i] = lo;
        if (i == r) Wr[j] = p;
      }
    }
  }
  __syncthreads();   // tm reads done; W arrays visible

  // ---- ph1.5: T0U = T0^T bf16, full-fill incl pad zeros (overwrites dead tm)
  {
    const float* T0b = T0 + (size_t)b*2500;
    for (int e=t; e<64*68; e+=256){
      int row = e/68, col = e - row*68;
      u16 v = 0;
      if (row < 50 && col < 50) v = f2bf(T0b[col*50 + row]);
      T0U[row][col] = v;
    }
  }
  __syncthreads();

  // ---- ph2: U-stripe = W (NT) T0U   [plain bf16]
  f32x4 uacc[4];
  #pragma unroll
  for (int ct=0;ct<4;++ct) uacc[ct] = (f32x4){0.f,0.f,0.f,0.f};
  #pragma unroll
  for (int ks=0; ks<2; ++ks){
    short8 a = ld8(&Whi[16*w + fr][ks*32 + fq*8]);
    #pragma unroll
    for (int ct=0;ct<4;++ct){
      short8 bb = ld8(&T0U[16*ct + fr][ks*32 + fq*8]);
      uacc[ct] = __builtin_amdgcn_mfma_f32_16x16x32_bf16(a, bb, uacc[ct], 0, 0, 0);
    }
  }
  __syncthreads();   // everyone done reading T0U before overwrite with U
  #pragma unroll
  for (int ct=0;ct<4;++ct)
    #pragma unroll
    for (int rr=0;rr<4;++rr)
      T0U[16*w + fq*4 + rr][16*ct + fr] = f2bf(uacc[ct][rr]);

  // ---- ph3: S-stripe = U (NT) W + m2  [plain bf16, fp32 in regs]
  f32x4 sacc[4];
  #pragma unroll
  for (int ct=0;ct<4;++ct) sacc[ct] = (f32x4){0.f,0.f,0.f,0.f};
  #pragma unroll
  for (int ks=0; ks<2; ++ks){
    short8 a = ld8(&T0U[16*w + fr][ks*32 + fq*8]);   // own stripe, self-written
    #pragma unroll
    for (int ct=0;ct<4;++ct){
      short8 bb = ld8(&Whi[16*ct + fr][ks*32 + fq*8]);
      sacc[ct] = __builtin_amdgcn_mfma_f32_16x16x32_bf16(a, bb, sacc[ct], 0, 0, 0);
    }
  }
  __syncthreads();   // NEW: all Whi reads done before P2lo overwrites the region

  // ---- ph4: in-register row-softmax; write P2hi (uni) / P2lo (Whi region)
  {
    const float* m2blk = m2 + (size_t)blk*2500;
    #pragma unroll
    for (int rr=0; rr<4; ++rr){
      const int row = 16*w + fq*4 + rr;
      float v[4];
      #pragma unroll
      for (int ct=0;ct<4;++ct){
        int col = 16*ct + fr;
        v[ct] = (row < 50 && col < 50) ? sacc[ct][rr] + m2blk[row*50 + col] : -1e30f;
      }
      float mx = fmaxf(fmaxf(v[0],v[1]), fmaxf(v[2],v[3]));
      mx = fmaxf(mx, __shfl_xor(mx,1,64));
      mx = fmaxf(mx, __shfl_xor(mx,2,64));
      mx = fmaxf(mx, __shfl_xor(mx,4,64));
      mx = fmaxf(mx, __shfl_xor(mx,8,64));
      float sm = 0.f;
      #pragma unroll
      for (int ct=0;ct<4;++ct){ v[ct] = __expf(v[ct]-mx); sm += v[ct]; }
      sm += __shfl_xor(sm,1,64);
      sm += __shfl_xor(sm,2,64);
      sm += __shfl_xor(sm,4,64);
      sm += __shfl_xor(sm,8,64);
      float inv = 1.0f/sm;
      #pragma unroll
      for (int ct=0;ct<4;++ct){
        float p = v[ct]*inv;
        u16 hi = f2bf(p); u16 lo = f2bf(p - bf2f(hi));
        P2hi[row][16*ct+fr] = hi;
        P2lo[row][16*ct+fr] = lo;
      }
    }
  }

  // ---- ph5: V2-stripe = P2 (NT) Wt  [3-term bf16 split]
  f32x4 vac[4];
  #pragma unroll
  for (int ct=0;ct<4;++ct) vac[ct] = (f32x4){0.f,0.f,0.f,0.f};
  #pragma unroll
  for (int ks=0; ks<2; ++ks){
    short8 ah = ld8(&P2hi[16*w + fr][ks*32 + fq*8]);  // own stripe, self-written
    short8 al = ld8(&P2lo[16*w + fr][ks*32 + fq*8]);
    #pragma unroll
    for (int ct=0;ct<4;++ct){
      short8 bh = ld8(&Wthi[16*ct + fr][ks*32 + fq*8]);
      short8 bl = ld8(&Wtlo[16*ct + fr][ks*32 + fq*8]);
      vac[ct] = __builtin_amdgcn_mfma_f32_16x16x32_bf16(ah, bh, vac[ct], 0, 0, 0);
      vac[ct] = __builtin_amdgcn_mfma_f32_16x16x32_bf16(ah, bl, vac[ct], 0, 0, 0);
      vac[ct] = __builtin_amdgcn_mfma_f32_16x16x32_bf16(al, bh, vac[ct], 0, 0, 0);
    }
  }
  {
    float* vout = V2buf + (size_t)blk*2500;
    #pragma unroll
    for (int rr=0;rr<4;++rr){
      const int row = 16*w + fq*4 + rr;
      if (row < 50){
        #pragma unroll
        for (int ct=0;ct<4;++ct){
          int col = 16*ct + fr;
          if (col < 50){
            vout[row*50 + col] = vac[ct][rr];
            if (row == r) V2r[col] = vac[ct][rr];
          }
        }
      }
    }
  }
  __syncthreads();

  // ---- ph6: d1 = Wr·h0 ; d2 = V2r·h0
  {
    float a1 = 0.f, a2 = 0.f;
    const float* h0b = h0 + (size_t)b*SLN*HSD;
    for (int j=0;j<50;++j){
      float hv = h0b[(size_t)j*HSD + t];
      a1 += Wr[j]*hv;
      a2 += V2r[j]*hv;
    }
    D123[(size_t)blk*768 + t]       = a1;   // d1
    D123[(size_t)blk*768 + 256 + t] = a2;   // d2
  }
}

// -------- stage E: sim3[k] = V2[b,k][i,:]·U0[b,i,:] + m3[b,i,i,k]; d3 --------
__global__ __launch_bounds__(256) void k_stageE(const float* __restrict__ U0,
                                                const float* __restrict__ V2buf,
                                                const float* __restrict__ m3,
                                                const float* __restrict__ h0,
                                                float* __restrict__ D123){
  const int blk = blockIdx.x;
  const int b = blk/SLN, i = blk - b*SLN;
  __shared__ float u[52];
  __shared__ float V[50][52];
  __shared__ float P3[52];
  __shared__ float w3[52];
  const int t = threadIdx.x;
  if (t < 50) u[t] = U0[(size_t)b*2500 + i*50 + t];
  for (int e=t; e<2500; e+=256){
    int k = e/50, j = e - k*50;
    V[k][j] = V2buf[((size_t)(b*SLN+k)*SLN + i)*SLN + j];
  }
  __syncthreads();
  if (t < 200){                       // sim3 (SCL folded into U0)
    int k = t>>2, s = t&3;
    float p = 0.f;
    for (int j=s; j<50; j+=4) p += V[k][j]*u[j];
    p += __shfl_xor(p,1,64); p += __shfl_xor(p,2,64);
    if (s==0) P3[k] = p + m3[((size_t)(b*SLN+i)*SLN + i)*SLN + k];
  }
  __syncthreads();
  if (t < 64){                        // softmax over 50
    float v = (t<50) ? P3[t] : -1e30f;
    float mx = v;
    for (int d=1; d<64; d<<=1) mx = fmaxf(mx, __shfl_xor(mx,d,64));
    float e_ = (t<50) ? __expf(v-mx) : 0.f;
    float sm = e_;
    for (int d=1; d<64; d<<=1) sm += __shfl_xor(sm,d,64);
    if (t<50) P3[t] = e_/sm;
  }
  __syncthreads();
  if (t < 200){                       // w3[j] = sum_k P3[k]*V[k][j]
    int j = t>>2, s = t&3;
    float p = 0.f;
    for (int k=s; k<50; k+=4) p += P3[k]*V[k][j];
    p += __shfl_xor(p,1,64); p += __shfl_xor(p,2,64);
    if (s==0) w3[j] = p;
  }
  __syncthreads();
  float acc = 0.f;
  for (int j=0;j<50;++j) acc += w3[j]*h0[(size_t)(b*SLN+j)*HSD + t];
  D123[(size_t)blk*768 + 512 + t] = acc;  // d3
}

// -------- row L2-normalize + cast to bf16; one wave per row --------
__global__ __launch_bounds__(256) void k_norm(const float* __restrict__ X,
                                              u16* __restrict__ out,
                                              int rows, int rowOffsetIn){
  int row = blockIdx.x*4 + (threadIdx.x>>6);
  if (row >= rows) return;
  int lane = threadIdx.x & 63;
  const float* x = X + (size_t)(row + rowOffsetIn)*HSD;
  float4 v = *(const float4*)&x[lane*4];
  float ss = v.x*v.x + v.y*v.y + v.z*v.z + v.w*v.w;
  for (int d=1; d<64; d<<=1) ss += __shfl_xor(ss,d,64);
  float rn = rsqrtf(ss);
  ushort4 o;
  o.x = f2bf(v.x*rn); o.y = f2bf(v.y*rn); o.z = f2bf(v.z*rn); o.w = f2bf(v.w*rn);
  *(ushort4*)&out[(size_t)row*HSD + lane*4] = o;
}

// -------- scores: out[m][n] = sum_k A[m,k]*B[n,k]  (r7 B-resident + T1 XCD swizzle) --------
// 1565 blocks; bijective XCD remap (m204): each XCD gets ~196 consecutive wgids,
// m-fastest within chunk -> each XCD re-reads a 2.5 MB B slice from its own L2.
__global__ __launch_bounds__(256) void k_scores(const u16* __restrict__ A,
                                                const u16* __restrict__ Bn,
                                                float* __restrict__ out){
  __shared__ __align__(16) u16 Bf[8][4096];   // 64 KB: whole K for this n-tile
  __shared__ __align__(16) u16 As[2][4096];   // 16 KB dbuf
  // ---- T1 bijective swizzle: nwg = 1565 = 8*195 + 5
  const int orig = blockIdx.x;
  const int xcd = orig & 7, jj = orig >> 3;
  const int wgid = (xcd < 5 ? xcd*196 : 5*196 + (xcd-5)*195) + jj;
  const int nidx = wgid / NMT;
  const int nb = nidx*128;
  const int mg = (wgid - nidx*NMT)*(NMT*128);
  const int t = threadIdx.x;
  const int l = t & 63, w = t >> 6;
  const int srow = l >> 2;                          // staging row within 16
  const int scol = ((l & 3) ^ (srow & 3)) * 8;      // pre-swizzled source unit
  const int wr = w >> 1, wc = w & 1;                // wave grid 2x2
  const int fr = l & 15, fq = l >> 4;               // fragment lane map
  const int fx = (fq ^ (fr & 3)) * 8;               // swizzled read unit

  // ---- prologue: stage all 8 B k-steps + A step 0
  #pragma unroll
  for (int ks=0; ks<8; ++ks){
    #pragma unroll
    for (int i_=0;i_<2;++i_){
      int seg = w*2 + i_;
      int row = seg*16 + srow;
      int brow = nb + row; if (brow > NOUT-1) brow = NOUT-1;
      __builtin_amdgcn_global_load_lds((guint*)&Bn[(size_t)brow*HSD + ks*32 + scol],
                                       (luint*)&Bf[ks][seg*512], 16, 0, 0);
    }
  }
  #define STAGEA(buf, s_) do{                                               \
    int m0_ = mg + ((s_)>>3)*128, k0_ = ((s_)&7)*32;                        \
    _Pragma("unroll")                                                       \
    for (int i_=0;i_<2;++i_){                                               \
      int seg_ = w*2 + i_;                                                  \
      int row_ = seg_*16 + srow;                                            \
      __builtin_amdgcn_global_load_lds(                                     \
        (guint*)&A[(size_t)(m0_+row_)*HSD + k0_ + scol],                    \
        (luint*)&As[buf][seg_*512], 16, 0, 0);                              \
    }                                                                       \
  }while(0)

  STAGEA(0, 0);

  f32x4 acc[4][4];
  #pragma unroll
  for (int m=0;m<4;++m)
    #pragma unroll
    for (int n=0;n<4;++n) acc[m][n] = (f32x4){0.f,0.f,0.f,0.f};

  for (int s=0; s<NMT*8; ++s){
    const int cur = s & 1, ks = s & 7;
    __syncthreads();                       // drains tile-s A loads (and B at s=0)
    if (s+1 < NMT*8) STAGEA(cur^1, s+1);   // prefetch next A under MFMA
    short8 af[4], bf[4];
    #pragma unroll
    for (int m=0;m<4;++m)
      af[m] = *(const short8*)&As[cur][(wr*64 + m*16 + fr)*32 + fx];
    #pragma unroll
    for (int n=0;n<4;++n)
      bf[n] = *(const short8*)&Bf[ks][(wc*64 + n*16 + fr)*32 + fx];
    #pragma unroll
    for (int m=0;m<4;++m)
      #pragma unroll
      for (int n=0;n<4;++n)
        acc[m][n] = __builtin_amdgcn_mfma_f32_16x16x32_bf16(af[m], bf[n], acc[m][n], 0, 0, 0);

    if (ks == 7){
      // ---- epilogue for m-tile (s>>3): C/D layout col=lane&15, row=(lane>>4)*4+reg
      const int mbase = mg + (s>>3)*128 + wr*64 + fq*4;
      #pragma unroll
      for (int n=0;n<4;++n){
        int col = nb + wc*64 + n*16 + fr;
        if (col < NOUT){
          #pragma unroll
          for (int m=0;m<4;++m){
            int row = mbase + m*16;
            #pragma unroll
            for (int rr=0; rr<4; ++rr)
              out[(size_t)(row+rr)*NOUT + col] = acc[m][n][rr];
          }
        }
      }
      #pragma unroll
      for (int m=0;m<4;++m)
        #pragma unroll
        for (int n=0;n<4;++n) acc[m][n] = (f32x4){0.f,0.f,0.f,0.f};
    }
  }
  #undef STAGEA
}

extern "C" void kernel_launch(void* const* d_in, const int* in_sizes, int n_in,
                              void* d_out, int out_size, void* d_ws, size_t ws_size,
                              hipStream_t stream){
  const int*   idx   = (const int*)  d_in[0];
  const float* m1    = (const float*)d_in[1];
  const float* m2    = (const float*)d_in[2];
  const float* m3    = (const float*)d_in[3];
  const float* emb   = (const float*)d_in[4];
  const float* sq_w  = (const float*)d_in[5];
  const float* sq_b  = (const float*)d_in[6];
  const float* sk_w  = (const float*)d_in[7];
  const float* sk_b  = (const float*)d_in[8];
  const float* tq_w  = (const float*)d_in[9];
  const float* tq_b  = (const float*)d_in[10];
  const float* tk_w  = (const float*)d_in[11];
  const float* tk_b  = (const float*)d_in[12];
  const float* aq_w  = (const float*)d_in[13];
  const float* aq_b  = (const float*)d_in[14];
  const float* ak_w  = (const float*)d_in[15];
  const float* ak_b  = (const float*)d_in[16];
  const float* cat_w = (const float*)d_in[17];
  const float* cat_b = (const float*)d_in[18];
  float* out = (float*)d_out;

  float* ws = (float*)d_ws;
  size_t off = 0;
  float* h0   = ws + off; off += (size_t)MROW*HSD;
  float* proj = ws + off; off += (size_t)MROW*1280;       // Sq0|Sk0|Qt0|Kt0|Ak0
  float* Wst  = ws + off; off += (size_t)1280*HSD;
  float* bst  = ws + off; off += 1280;
  float* S0   = ws + off; off += (size_t)BSZ*2500;
  float* T0   = ws + off; off += (size_t)BSZ*2500;
  float* U0   = ws + off; off += (size_t)BSZ*2500;
  float* V2   = ws + off; off += (size_t)MROW*2500;
  float* D123 = ws + off; off += (size_t)MROW*768;
  float* q3d  = ws + off; off += (size_t)MROW*HSD;
  float* a32  = ws + off; off += (size_t)MROW*HSD;
  u16*   abf  = (u16*)(ws + off); off += (size_t)MROW*HSD/2;
  u16*   bnf  = (u16*)(ws + off); off += ((size_t)NOUT*HSD+1)/2;
  (void)ws_size; (void)in_sizes; (void)n_in; (void)out_size;

  hipMemcpyAsync(Wst + 0*65536, sq_w, 65536*sizeof(float), hipMemcpyDeviceToDevice, stream);
  hipMemcpyAsync(Wst + 1*65536, sk_w, 65536*sizeof(float), hipMemcpyDeviceToDevice, stream);
  hipMemcpyAsync(Wst + 2*65536, tq_w, 65536*sizeof(float), hipMemcpyDeviceToDevice, stream);
  hipMemcpyAsync(Wst + 3*65536, tk_w, 65536*sizeof(float), hipMemcpyDeviceToDevice, stream);
  hipMemcpyAsync(Wst + 4*65536, ak_w, 65536*sizeof(float), hipMemcpyDeviceToDevice, stream);
  hipMemcpyAsync(bst + 0*256, sq_b, 256*sizeof(float), hipMemcpyDeviceToDevice, stream);
  hipMemcpyAsync(bst + 1*256, sk_b, 256*sizeof(float), hipMemcpyDeviceToDevice, stream);
  hipMemcpyAsync(bst + 2*256, tq_b, 256*sizeof(float), hipMemcpyDeviceToDevice, stream);
  hipMemcpyAsync(bst + 3*256, tk_b, 256*sizeof(float), hipMemcpyDeviceToDevice, stream);
  hipMemcpyAsync(bst + 4*256, ak_b, 256*sizeof(float), hipMemcpyDeviceToDevice, stream);

  k_gather<<<MROW, 256, 0, stream>>>(idx, emb, h0);
  k_gemm  <<<dim3(50,20), 256, 0, stream>>>(h0, HSD, Wst, HSD, bst, proj, 1280, HSD);
  k_s0t0  <<<dim3(BSZ,2), 256, 0, stream>>>(proj, S0, T0);
  k_stageD<<<MROW, 256, 0, stream>>>(S0, m1, T0, m2, h0, V2, D123);
  k_gemm  <<<dim3(50,4), 256, 0, stream>>>(D123+256, 768, aq_w, HSD, aq_b, q3d, HSD, HSD);
  k_u0    <<<BSZ, 256, 0, stream>>>(q3d, proj, U0);
  k_stageE<<<MROW, 256, 0, stream>>>(U0, V2, m3, h0, D123);
  k_gemm  <<<dim3(50,4), 256, 0, stream>>>(D123, 768, cat_w, 768, cat_b, a32, HSD, 768);
  k_norm  <<<MROW/4, 256, 0, stream>>>(a32, abf, MROW, 0);
  k_norm  <<<10000, 256, 0, stream>>>(emb, bnf, NOUT, 1);
  k_scores<<<1565, 256, 0, stream>>>(abf, bnf, out);
}